// Round 7
// baseline (1883.410 us; speedup 1.0000x reference)
//
#include <hip/hip_runtime.h>

// B=8, S=128, IN=512, D=1024, E=4, NH=16, DH=64; tokens N=1024
// bf16 weights (transposed [N][K]) + MFMA 16x16x32; fp32 accumulate.
// LSTM: persistent kernel, Wh in regs, relaxed-atomic h exchange,
// single-hop all-to-all barrier with sc0 (L2-local) tag polling +
// timeout escalation to agent scope (placement-independent correctness).
// GEMM: double-buffered LDS with counted vmcnt (T3 2-phase).

typedef __attribute__((ext_vector_type(8))) short short8v;
typedef __attribute__((ext_vector_type(4))) float float4v;

__device__ __forceinline__ float bf2f(unsigned short u) {
    unsigned int x = ((unsigned int)u) << 16;
    return __builtin_bit_cast(float, x);
}
__device__ __forceinline__ unsigned short f2bf(float f) {
    unsigned int u = __builtin_bit_cast(unsigned int, f);
    u += 0x7fffu + ((u >> 16) & 1u);
    return (unsigned short)(u >> 16);
}
__device__ __forceinline__ void gload_lds16(const unsigned short* g, unsigned short* lds) {
    __builtin_amdgcn_global_load_lds(
        (const __attribute__((address_space(1))) unsigned int*)g,
        (__attribute__((address_space(3))) unsigned int*)lds, 16, 0, 0);
}
// sc0-only load: bypasses L1, reads (possibly local-XCD) L2. Used ONLY for
// monotonic tag polls where staleness delays but cannot corrupt.
__device__ __forceinline__ unsigned ld_tag_sc0(const unsigned* p) {
    unsigned v;
    asm volatile("global_load_dword %0, %1, off sc0\n\ts_waitcnt vmcnt(0)"
                 : "=v"(v) : "v"(p) : "memory");
    return v;
}

// ---------------- fp32 -> bf16 elementwise convert -------------------------
__global__ __launch_bounds__(256) void cvt_bf16_kernel(
    const float* __restrict__ in, unsigned short* __restrict__ out, int n4)
{
    int i = blockIdx.x * 256 + threadIdx.x;
    if (i >= n4) return;
    float4 v = *reinterpret_cast<const float4*>(&in[i * 4]);
    ushort4 o;
    o.x = f2bf(v.x); o.y = f2bf(v.y); o.z = f2bf(v.z); o.w = f2bf(v.w);
    *reinterpret_cast<ushort4*>(&out[i * 4]) = o;
}

// ---------------- batched W[K][N] fp32 -> Wt[N][K] bf16 (all weights) ------
struct TransJobs {
    const float* src[14];
    unsigned short* dst[14];
    int K[14], N[14];
    int prefix[15];
    long sWe[14], sTe[14];
};

__global__ __launch_bounds__(256) void transpose_all(TransJobs J)
{
    __shared__ float tile[32][33];
    int bid = blockIdx.x;
    int j = 0;
    #pragma unroll
    for (int i = 0; i < 14; ++i) if (bid >= J.prefix[i + 1]) j = i + 1;
    int lb = bid - J.prefix[j];
    int K = J.K[j], N = J.N[j];
    int tn = N >> 5, tk = K >> 5;
    int e = lb / (tn * tk), rem = lb % (tn * tk);
    int ky = rem / tn, nx = rem % tn;
    const float* W = J.src[j] + (long)e * J.sWe[j];
    unsigned short* Wt = J.dst[j] + (long)e * J.sTe[j];
    int k0 = ky * 32, n0 = nx * 32;
    int tx = threadIdx.x & 31, ty = threadIdx.x >> 5;
    #pragma unroll
    for (int i = 0; i < 32; i += 8)
        tile[ty + i][tx] = W[(long)(k0 + ty + i) * N + n0 + tx];
    __syncthreads();
    #pragma unroll
    for (int i = 0; i < 32; i += 8)
        Wt[(long)(n0 + ty + i) * K + k0 + tx] = f2bf(tile[tx][ty + i]);
}

// ---------------- router (fp32) --------------------------------------------
__global__ __launch_bounds__(64) void router_kernel(
    const float* __restrict__ x, const float* __restrict__ rw,
    const float* __restrict__ rb, float* __restrict__ router)
{
    int token = blockIdx.x;
    int lane = threadIdx.x;
    float a0 = 0.f, a1 = 0.f, a2 = 0.f, a3 = 0.f;
    const float* xp = x + (long)token * 512;
    for (int i = lane; i < 512; i += 64) {
        float xv = xp[i];
        const float* w = rw + (long)i * 4;
        a0 += xv * w[0]; a1 += xv * w[1]; a2 += xv * w[2]; a3 += xv * w[3];
    }
    #pragma unroll
    for (int off = 32; off; off >>= 1) {
        a0 += __shfl_down(a0, off); a1 += __shfl_down(a1, off);
        a2 += __shfl_down(a2, off); a3 += __shfl_down(a3, off);
    }
    if (lane == 0) {
        a0 += rb[0]; a1 += rb[1]; a2 += rb[2]; a3 += rb[3];
        float m = fmaxf(fmaxf(a0, a1), fmaxf(a2, a3));
        float e0 = __expf(a0 - m), e1 = __expf(a1 - m);
        float e2 = __expf(a2 - m), e3 = __expf(a3 - m);
        float inv = 1.f / (e0 + e1 + e2 + e3);
        *reinterpret_cast<float4*>(&router[token * 4]) =
            make_float4(e0 * inv, e1 * inv, e2 * inv, e3 * inv);
    }
}

// ---------------- MFMA bf16 GEMM: C = act(A@W + bias) [*mul] ---------------
// Double-buffered LDS, counted vmcnt(8), loads in flight across barriers.
template <int OUTBF>
__global__ __launch_bounds__(256) void gemm_bf16(
    const unsigned short* __restrict__ A, const unsigned short* __restrict__ Wt,
    const float* __restrict__ bias, const float* __restrict__ bias2,
    const unsigned short* __restrict__ mul,
    void* __restrict__ Cv, int N, int K, int lda, int nsplit,
    long sAe, long sWe, long sBe, long sMe, long sCe, int act)
{
    __shared__ unsigned short As[2][128 * 64];
    __shared__ unsigned short Bs[2][128 * 64];
    int e = blockIdx.z;
    A += (long)e * sAe; Wt += (long)e * sWe;
    bias += (long)e * sBe; bias2 += (long)e * sBe;
    if (mul) mul += (long)e * sMe;
    int tid = threadIdx.x;
    int row0 = blockIdx.y * 128, col0 = blockIdx.x * 128;
    int wid = tid >> 6, lane = tid & 63;
    int wr = wid >> 1, wc = wid & 1;
    int l15 = lane & 15, l4 = lane >> 4;
    int r8 = lane >> 3, sg = lane & 7;
    float4v acc[4][4];
    #pragma unroll
    for (int i = 0; i < 4; ++i)
        #pragma unroll
        for (int j = 0; j < 4; ++j) acc[i][j] = (float4v){0.f, 0.f, 0.f, 0.f};

    auto STAGE = [&](int buf, int k0) {
        #pragma unroll
        for (int c = 0; c < 4; ++c) {
            int chunk = wid * 4 + c;
            int rowA = chunk * 8 + r8;
            int segA = (sg ^ (rowA & 7)) * 8;
            gload_lds16(A + (long)(row0 + rowA) * lda + k0 + segA,
                        (unsigned short*)((char*)As[buf] + chunk * 1024));
            gload_lds16(Wt + (long)(col0 + rowA) * K + k0 + segA,
                        (unsigned short*)((char*)Bs[buf] + chunk * 1024));
        }
    };
    int nt = K >> 6;
    STAGE(0, 0);
    for (int t = 0; t < nt; ++t) {
        int cur = t & 1;
        if (t + 1 < nt) {
            STAGE(cur ^ 1, (t + 1) << 6);
            asm volatile("s_waitcnt vmcnt(8)" ::: "memory");
        } else {
            asm volatile("s_waitcnt vmcnt(0)" ::: "memory");
        }
        __builtin_amdgcn_s_barrier();
        __builtin_amdgcn_sched_barrier(0);
        #pragma unroll
        for (int kk = 0; kk < 2; ++kk) {
            short8v af[4], bq[4];
            int bytec = kk * 64 + l4 * 16;
            #pragma unroll
            for (int m = 0; m < 4; ++m) {
                int r = wr * 64 + m * 16 + l15;
                af[m] = *reinterpret_cast<const short8v*>(
                    (char*)As[cur] + r * 128 + (bytec ^ ((r & 7) << 4)));
            }
            #pragma unroll
            for (int n = 0; n < 4; ++n) {
                int r = wc * 64 + n * 16 + l15;
                bq[n] = *reinterpret_cast<const short8v*>(
                    (char*)Bs[cur] + r * 128 + (bytec ^ ((r & 7) << 4)));
            }
            #pragma unroll
            for (int m = 0; m < 4; ++m)
                #pragma unroll
                for (int n = 0; n < 4; ++n)
                    acc[m][n] = __builtin_amdgcn_mfma_f32_16x16x32_bf16(
                        af[m], bq[n], acc[m][n], 0, 0, 0);
        }
        __builtin_amdgcn_sched_barrier(0);
        __builtin_amdgcn_s_barrier();
    }
    float* Cf = (float*)Cv + (long)e * sCe;
    unsigned short* Cb = (unsigned short*)Cv + (long)e * sCe;
    #pragma unroll
    for (int n = 0; n < 4; ++n) {
        int col = col0 + wc * 64 + n * 16 + l15;
        float bia = (col < nsplit) ? bias[col] : bias2[col - nsplit];
        #pragma unroll
        for (int m = 0; m < 4; ++m) {
            #pragma unroll
            for (int r = 0; r < 4; ++r) {
                long row = row0 + wr * 64 + m * 16 + l4 * 4 + r;
                float v = acc[m][n][r] + bia;
                if (act == 1) v = fmaxf(v, 0.f);
                else if (act == 2) v = 1.f / (1.f + __expf(-v));
                else if (act == 3) v = tanhf(v);
                if (mul) v *= bf2f(mul[row * N + col]);
                if (OUTBF) Cb[row * N + col] = f2bf(v);
                else       Cf[row * N + col] = v;
            }
        }
    }
}

// ---------------- LayerNorm bf16 in/out (DIM=1024) -------------------------
template <int DIM>
__global__ __launch_bounds__(256) void ln_bf16(
    unsigned short* __restrict__ buf, const float* __restrict__ g,
    const float* __restrict__ beta)
{
    constexpr int PT = DIM / 256;
    __shared__ float sbuf[4];
    int row = blockIdx.x, e = row >> 10;
    unsigned short* p = buf + (long)row * DIM;
    const float* gp = g + (long)e * DIM;
    const float* bp = beta + (long)e * DIM;
    int tid = threadIdx.x;
    float v[PT];
    ushort4 u = *reinterpret_cast<const ushort4*>(p + tid * PT);
    v[0] = bf2f(u.x); v[1] = bf2f(u.y); v[2] = bf2f(u.z); v[3] = bf2f(u.w);
    float s = v[0] + v[1] + v[2] + v[3];
    #pragma unroll
    for (int off = 32; off; off >>= 1) s += __shfl_down(s, off);
    if ((tid & 63) == 0) sbuf[tid >> 6] = s;
    __syncthreads();
    float mean = (sbuf[0] + sbuf[1] + sbuf[2] + sbuf[3]) / (float)DIM;
    __syncthreads();
    float vs = 0.f;
    #pragma unroll
    for (int i = 0; i < PT; ++i) { float d = v[i] - mean; vs += d * d; }
    #pragma unroll
    for (int off = 32; off; off >>= 1) vs += __shfl_down(vs, off);
    if ((tid & 63) == 0) sbuf[tid >> 6] = vs;
    __syncthreads();
    float var = (sbuf[0] + sbuf[1] + sbuf[2] + sbuf[3]) / (float)DIM;
    float rstd = rsqrtf(var + 1e-5f);
    ushort4 o;
    o.x = f2bf((v[0] - mean) * rstd * gp[tid * PT + 0] + bp[tid * PT + 0]);
    o.y = f2bf((v[1] - mean) * rstd * gp[tid * PT + 1] + bp[tid * PT + 1]);
    o.z = f2bf((v[2] - mean) * rstd * gp[tid * PT + 2] + bp[tid * PT + 2]);
    o.w = f2bf((v[3] - mean) * rstd * gp[tid * PT + 3] + bp[tid * PT + 3]);
    *reinterpret_cast<ushort4*>(p + tid * PT) = o;
}

// ---------------- LayerNorm fp32 in-place (DIM=512 final) ------------------
template <int DIM>
__global__ __launch_bounds__(256) void ln_kernel(
    float* __restrict__ buf, const float* __restrict__ g,
    const float* __restrict__ beta)
{
    constexpr int PT = DIM / 256;
    __shared__ float sbuf[4];
    int row = blockIdx.x, e = row >> 10;
    float* p = buf + (long)row * DIM;
    const float* gp = g + (long)e * DIM;
    const float* bp = beta + (long)e * DIM;
    int tid = threadIdx.x;
    float v[PT];
    float s = 0.f;
    #pragma unroll
    for (int i = 0; i < PT; ++i) { v[i] = p[tid + i * 256]; s += v[i]; }
    #pragma unroll
    for (int off = 32; off; off >>= 1) s += __shfl_down(s, off);
    if ((tid & 63) == 0) sbuf[tid >> 6] = s;
    __syncthreads();
    float mean = (sbuf[0] + sbuf[1] + sbuf[2] + sbuf[3]) / (float)DIM;
    __syncthreads();
    float vs = 0.f;
    #pragma unroll
    for (int i = 0; i < PT; ++i) { float d = v[i] - mean; vs += d * d; }
    #pragma unroll
    for (int off = 32; off; off >>= 1) vs += __shfl_down(vs, off);
    if ((tid & 63) == 0) sbuf[tid >> 6] = vs;
    __syncthreads();
    float var = (sbuf[0] + sbuf[1] + sbuf[2] + sbuf[3]) / (float)DIM;
    float rstd = rsqrtf(var + 1e-5f);
    #pragma unroll
    for (int i = 0; i < PT; ++i)
        p[tid + i * 256] = (v[i] - mean) * rstd * gp[tid + i * 256] + bp[tid + i * 256];
}

// ---------------- fused attention, bf16 in/out -----------------------------
__global__ __launch_bounds__(128) void attn_bf16(
    const unsigned short* __restrict__ qkv, unsigned short* __restrict__ o)
{
    __shared__ __align__(16) float Ks[128][64];
    __shared__ __align__(16) float Vs[128][64];
    int id = blockIdx.x;
    int hd = id & 15, b = (id >> 4) & 7, e = id >> 7;
    int tid = threadIdx.x;
    const long base = ((long)e * 1024 + b * 128) * 3072 + hd * 64;
    #pragma unroll
    for (int i = 0; i < 8; ++i) {
        int idx = i * 128 + tid;
        int row = idx >> 3, f8 = (idx & 7) * 8;
        short8v kv = *reinterpret_cast<const short8v*>(&qkv[base + (long)row * 3072 + 1024 + f8]);
        short8v vv = *reinterpret_cast<const short8v*>(&qkv[base + (long)row * 3072 + 2048 + f8]);
        #pragma unroll
        for (int j = 0; j < 8; ++j) {
            Ks[row][f8 + j] = bf2f((unsigned short)kv[j]);
            Vs[row][f8 + j] = bf2f((unsigned short)vv[j]);
        }
    }
    __syncthreads();
    float q[64];
    #pragma unroll
    for (int f = 0; f < 8; ++f) {
        short8v qv = *reinterpret_cast<const short8v*>(&qkv[base + (long)tid * 3072 + f * 8]);
        #pragma unroll
        for (int j = 0; j < 8; ++j) q[f * 8 + j] = bf2f((unsigned short)qv[j]);
    }
    float m = -__builtin_huge_valf(), l = 0.f;
    float oa[64];
    #pragma unroll
    for (int d = 0; d < 64; ++d) oa[d] = 0.f;
    for (int j = 0; j < 128; ++j) {
        float s = 0.f;
        #pragma unroll
        for (int d = 0; d < 64; ++d) s = fmaf(q[d], Ks[j][d], s);
        s *= 0.125f;
        float mn = fmaxf(m, s);
        float corr = __expf(m - mn);
        float pj = __expf(s - mn);
        l = l * corr + pj;
        #pragma unroll
        for (int d = 0; d < 64; ++d) oa[d] = oa[d] * corr + pj * Vs[j][d];
        m = mn;
    }
    float inv = 1.f / l;
    unsigned short* op = o + ((long)e * 1024 + b * 128 + tid) * 1024 + hd * 64;
    #pragma unroll
    for (int f = 0; f < 8; ++f) {
        short8v ov;
        #pragma unroll
        for (int j = 0; j < 8; ++j) ov[j] = (short)f2bf(oa[f * 8 + j] * inv);
        *reinterpret_cast<short8v*>(&op[f * 8]) = ov;
    }
}

// ---------------- persistent LSTM ------------------------------------------
// grid 512 x 512thr; chain ed = bid&7 (same-XCD under round-robin dispatch),
// cb = bid>>3 (16 h-cols each). Wh frags in regs.
// h exchange: relaxed agent-scope atomics. Barrier: single-hop all-to-all
// with monotonic tags; polls use sc0 (local-L2) loads with timeout
// escalation to agent scope — staleness can only delay, never corrupt.
__global__ __launch_bounds__(512, 4) void lstm_persistent(
    const unsigned short* __restrict__ pre, const unsigned short* __restrict__ whtf,
    const unsigned short* __restrict__ whtb, unsigned short* __restrict__ hstate,
    unsigned short* __restrict__ memb, unsigned int* __restrict__ sync)
{
    __shared__ unsigned short hA[16 * 1024];       // 32KB swizzled A-operand
    __shared__ float zred[4][2][8][16];            // gate, khalf, batch, col
    int bid = blockIdx.x;
    int ed = bid & 7, cb = bid >> 3;
    int e = ed >> 1, dir = ed & 1;
    const unsigned short* Wt = (dir ? whtb : whtf) + (long)e * 4096 * 1024;
    unsigned int* arr = sync + ed * 64;            // [8][64] arrival slots
    int tid = threadIdx.x;
    int w = tid >> 6, lane = tid & 63, l15 = lane & 15, l4 = lane >> 4;
    int g = w >> 1, kh = w & 1;
    // one-time: weight fragments into registers
    short8v wf[16];
    const unsigned short* wp =
        Wt + ((long)(g * 1024 + cb * 16 + l15)) * 1024 + kh * 512 + l4 * 8;
    #pragma unroll
    for (int ks = 0; ks < 16; ++ks)
        wf[ks] = *reinterpret_cast<const short8v*>(wp + ks * 32);
    // one-time: zero pad rows 8..15 of hA
    short8v z8 = {0, 0, 0, 0, 0, 0, 0, 0};
    for (int i = tid; i < 8 * 128; i += 512) {
        int r = 8 + (i >> 7), sb = (i & 127) * 16;
        *reinterpret_cast<short8v*>((char*)hA + r * 2048 + (sb ^ ((r & 7) << 4))) = z8;
    }
    float c0 = 0.f, c1 = 0.f;                      // c-state (gate threads)
    int gp = tid & 7, gb = tid >> 3;               // gate mapping (tid<64)
    for (int s = 0; s < 128; ++s) {
        int t = dir ? 127 - s : s;
        const unsigned long long* hin64 = reinterpret_cast<const unsigned long long*>(
            hstate + (long)(s & 1) * 65536 + (long)ed * 8192);
        __syncthreads();
        // stage h(s-1): coherent 8B loads -> swizzled LDS
        #pragma unroll
        for (int i = 0; i < 4; ++i) {
            int idx = tid + 512 * i;               // 0..2047 (8B units)
            unsigned long long v = __hip_atomic_load(
                hin64 + idx, __ATOMIC_RELAXED, __HIP_MEMORY_SCOPE_AGENT);
            int r = idx >> 8, sb = (idx & 255) * 8;
            *reinterpret_cast<unsigned long long*>(
                (char*)hA + r * 2048 + (sb ^ ((r & 7) << 4))) = v;
        }
        // prefetch pre for gate threads
        float pz[8];
        if (tid < 64) {
            const unsigned short* prow =
                pre + (((long)e * 1024) + gb * 128 + t) * 8192 + dir * 4096 + cb * 16 + gp * 2;
            #pragma unroll
            for (int gg = 0; gg < 4; ++gg) {
                unsigned int u = *reinterpret_cast<const unsigned int*>(prow + gg * 1024);
                pz[gg * 2]     = bf2f((unsigned short)(u & 0xffff));
                pz[gg * 2 + 1] = bf2f((unsigned short)(u >> 16));
            }
        }
        __syncthreads();
        // MFMA: acc = h @ Wh[:, mycols]
        float4v acc = (float4v){0.f, 0.f, 0.f, 0.f};
        int abase = l15 * 2048, aswz = (l15 & 7) << 4;
        #pragma unroll
        for (int ks = 0; ks < 16; ++ks) {
            short8v a = *reinterpret_cast<const short8v*>(
                (char*)hA + abase + (((kh * 512 + ks * 32) * 2 + l4 * 16) ^ aswz));
            acc = __builtin_amdgcn_mfma_f32_16x16x32_bf16(a, wf[ks], acc, 0, 0, 0);
        }
        if (l4 < 2) {
            #pragma unroll
            for (int r = 0; r < 4; ++r)
                zred[g][kh][l4 * 4 + r][l15] = acc[r];
        }
        __syncthreads();
        if (tid < 64) {
            int col0 = gp * 2;
            float h2[2];
            #pragma unroll
            for (int cc = 0; cc < 2; ++cc) {
                int col = col0 + cc;
                float zi = zred[0][0][gb][col] + zred[0][1][gb][col] + pz[0 + cc];
                float zf = zred[1][0][gb][col] + zred[1][1][gb][col] + pz[2 + cc];
                float zg = zred[2][0][gb][col] + zred[2][1][gb][col] + pz[4 + cc];
                float zo = zred[3][0][gb][col] + zred[3][1][gb][col] + pz[6 + cc];
                float ig = 1.f / (1.f + __expf(-zi));
                float fg = 1.f / (1.f + __expf(-zf));
                float gv = tanhf(zg);
                float og = 1.f / (1.f + __expf(-zo));
                float cv = cc ? c1 : c0;
                cv = fg * cv + ig * gv;
                if (cc) c1 = cv; else c0 = cv;
                h2[cc] = og * tanhf(cv);
            }
            unsigned int hv = (unsigned int)f2bf(h2[0]) | ((unsigned int)f2bf(h2[1]) << 16);
            int hcol = cb * 16 + col0;
            unsigned int* hout32 = reinterpret_cast<unsigned int*>(
                hstate + (long)((s & 1) ^ 1) * 65536 + (long)ed * 8192);
            __hip_atomic_store(hout32 + (gb * 1024 + hcol) / 2, hv,
                               __ATOMIC_RELAXED, __HIP_MEMORY_SCOPE_AGENT);
            *reinterpret_cast<unsigned int*>(
                memb + (((long)e * 8 + gb) * 128 + t) * 2048 + dir * 1024 + hcol) = hv;
        }
        if (s == 127) break;           // last step: no consumer, skip barrier
        __syncthreads();               // drains vmcnt: h stores at coherence pt
        // single-hop all-to-all: signal own slot, wave0 sweeps all 64.
        // Poll with sc0 (local L2) first; escalate to agent scope on timeout.
        if (tid == 0)
            __hip_atomic_store(arr + cb, (unsigned)(s + 1), __ATOMIC_RELAXED,
                               __HIP_MEMORY_SCOPE_AGENT);
        if (tid < 64) {
            const unsigned* tagp = arr + tid;
            unsigned want = (unsigned)(s + 1);
            unsigned v = ld_tag_sc0(tagp);
            int spins = 0;
            while (v < want) {
                __builtin_amdgcn_s_sleep(1);
                if (++spins < 48)
                    v = ld_tag_sc0(tagp);
                else
                    v = __hip_atomic_load(tagp, __ATOMIC_RELAXED,
                                          __HIP_MEMORY_SCOPE_AGENT);
            }
        }
        // top-of-loop __syncthreads() completes the barrier block-wide
    }
}

// ---------------- routed combine (fp32) ------------------------------------
__global__ __launch_bounds__(256) void combine_kernel(
    const float* __restrict__ outs, const float* __restrict__ router,
    float* __restrict__ out)
{
    int idx = blockIdx.x * 256 + threadIdx.x;
    int token = idx >> 7, q = (idx & 127) * 4;
    float4 r = *reinterpret_cast<const float4*>(&router[token * 4]);
    const float* bp = outs + (long)token * 512 + q;
    float4 v0 = *reinterpret_cast<const float4*>(bp);
    float4 v1 = *reinterpret_cast<const float4*>(bp + 524288);
    float4 v2 = *reinterpret_cast<const float4*>(bp + 1048576);
    float4 v3 = *reinterpret_cast<const float4*>(bp + 1572864);
    float4 a;
    a.x = r.x * v0.x + r.y * v1.x + r.z * v2.x + r.w * v3.x;
    a.y = r.x * v0.y + r.y * v1.y + r.z * v2.y + r.w * v3.y;
    a.z = r.x * v0.z + r.y * v1.z + r.z * v2.z + r.w * v3.z;
    a.w = r.x * v0.w + r.y * v1.w + r.z * v2.w + r.w * v3.w;
    *reinterpret_cast<float4*>(&out[(long)token * 512 + q]) = a;
}

extern "C" void kernel_launch(void* const* d_in, const int* in_sizes, int n_in,
                              void* d_out, int out_size, void* d_ws, size_t ws_size,
                              hipStream_t stream)
{
    (void)in_sizes; (void)n_in; (void)out_size; (void)ws_size;
    const float* x        = (const float*)d_in[0];
    const float* router_w = (const float*)d_in[1];
    const float* router_b = (const float*)d_in[2];
    const float* enc_w1   = (const float*)d_in[3];
    const float* enc_b1   = (const float*)d_in[4];
    const float* enc_w2   = (const float*)d_in[5];
    const float* enc_b2   = (const float*)d_in[6];
    const float* enc_g    = (const float*)d_in[7];
    const float* enc_beta = (const float*)d_in[8];
    const float* aiw      = (const float*)d_in[9];
    const float* aib      = (const float*)d_in[10];
    const float* aow      = (const float*)d_in[11];
    const float* aob      = (const float*)d_in[12];
    const float* wif      = (const float*)d_in[13];
    const float* whf      = (const float*)d_in[14];
    const float* bfv      = (const float*)d_in[15];
    const float* wib      = (const float*)d_in[16];
    const float* whb      = (const float*)d_in[17];
    const float* bbv      = (const float*)d_in[18];
    const float* sw1      = (const float*)d_in[19];
    const float* sb1      = (const float*)d_in[20];
    const float* sw2      = (const float*)d_in[21];
    const float* sb2      = (const float*)d_in[22];
    const float* tw1      = (const float*)d_in[23];
    const float* tb1      = (const float*)d_in[24];
    const float* tw2      = (const float*)d_in[25];
    const float* tb2      = (const float*)d_in[26];
    const float* dw1      = (const float*)d_in[27];
    const float* db1      = (const float*)d_in[28];
    const float* dw2      = (const float*)d_in[29];
    const float* db2      = (const float*)d_in[30];
    const float* dg       = (const float*)d_in[31];
    const float* dbeta    = (const float*)d_in[32];
    float* out = (float*)d_out;

    const long m = 1024L * 1024L;
    unsigned short* U = (unsigned short*)d_ws;
    unsigned short* ew1T = U;               // 2m
    unsigned short* ew2T = U + 2 * m;       // 4m
    unsigned short* aiwT = U + 6 * m;       // 12m
    unsigned short* aowT = U + 18 * m;      // 4m
    unsigned short* wiT  = U + 22 * m;      // 32m: [e][fwd4096|bwd4096][1024]
    unsigned short* whtf = U + 54 * m;      // 16m
    unsigned short* whtb = U + 70 * m;      // 16m
    unsigned short* gw1T = U + 86 * m;      // 16m: per-e 4m slab (sw1|tw1 cols)
    unsigned short* sw2T = U + 102 * m;     // 4m
    unsigned short* tw2T = U + 106 * m;     // 4m
    unsigned short* dw1T = U + 110 * m;     // 4m
    unsigned short* dw2T = U + 114 * m;     // 2m
    unsigned short* xb   = U + 116 * m;     // 0.5m
    unsigned short* hbuf = xb + 524288;     // 4m
    unsigned short* t1   = hbuf + 4 * m;    // 4m
    unsigned short* t2   = t1 + 4 * m;      // 4m
    unsigned short* pre  = t2 + 4 * m;      // 32m (early: qkv; late: gate1 out)
    unsigned short* memb = pre + 32 * m;    // 8m
    unsigned short* hstate = memb + 8 * m;  // 262144 ushorts (2 buffers)
    float* F      = (float*)(U + 170 * m);
    float* outs   = F;                      // 2m floats
    float* router = outs + 2 * m;           // 4096
    unsigned int* syncv = (unsigned int*)(router + 4096);  // 1024 uints

    hipMemsetAsync(hstate, 0, 65536 * sizeof(unsigned short), stream);
    hipMemsetAsync(syncv, 0, 1024 * sizeof(unsigned int), stream);

    // one-time conversions: x + all weights (one batched dispatch)
    cvt_bf16_kernel<<<512, 256, 0, stream>>>(x, xb, 131072);
    {
        TransJobs J;
        const float* srcs[14] = {enc_w1, enc_w2, aiw, aow, wif, wib, whf, whb,
                                 sw1, tw1, sw2, tw2, dw1, dw2};
        unsigned short* dsts[14] = {ew1T, ew2T, aiwT, aowT, wiT, wiT + 4096 * 1024L,
                                    whtf, whtb, gw1T, gw1T + 2 * m, sw2T, tw2T, dw1T, dw2T};
        int Ks[14] = {512, 1024, 1024, 1024, 1024, 1024, 1024, 1024,
                      2048, 2048, 1024, 1024, 1024, 1024};
        int Ns[14] = {1024, 1024, 3072, 1024, 4096, 4096, 4096, 4096,
                      1024, 1024, 1024, 1024, 1024, 512};
        long sWes[14] = {512 * 1024L, m, 3 * m, m, 4 * m, 4 * m, 4 * m, 4 * m,
                         2 * m, 2 * m, m, m, m, 512 * 1024L};
        long sTes[14] = {512 * 1024L, m, 3 * m, m, 8 * m, 8 * m, 4 * m, 4 * m,
                         4 * m, 4 * m, m, m, m, 512 * 1024L};
        int pfx = 0;
        J.prefix[0] = 0;
        for (int i = 0; i < 14; ++i) {
            J.src[i] = srcs[i]; J.dst[i] = dsts[i];
            J.K[i] = Ks[i]; J.N[i] = Ns[i];
            J.sWe[i] = sWes[i]; J.sTe[i] = sTes[i];
            pfx += (Ns[i] >> 5) * (Ks[i] >> 5) * 4;
            J.prefix[i + 1] = pfx;
        }
        transpose_all<<<pfx, 256, 0, stream>>>(J);
    }

    router_kernel<<<1024, 64, 0, stream>>>(x, router_w, router_b, router);

    // encoder
    gemm_bf16<1><<<dim3(8, 8, 4), 256, 0, stream>>>(xb, ew1T, enc_b1, enc_b1, nullptr, t1,
        1024, 512, 512, 1024, 0L, 512 * 1024L, 1024L, 0L, m, 1);
    gemm_bf16<1><<<dim3(8, 8, 4), 256, 0, stream>>>(t1, ew2T, enc_b2, enc_b2, nullptr, hbuf,
        1024, 1024, 1024, 1024, m, m, 1024L, 0L, m, 0);
    ln_bf16<1024><<<4096, 256, 0, stream>>>(hbuf, enc_g, enc_beta);
    // attention (qkv in pre region)
    gemm_bf16<1><<<dim3(24, 8, 4), 256, 0, stream>>>(hbuf, aiwT, aib, aib, nullptr, pre,
        3072, 1024, 1024, 3072, m, 3 * m, 3072L, 0L, 3 * m, 0);
    attn_bf16<<<512, 128, 0, stream>>>(pre, t1);
    gemm_bf16<1><<<dim3(8, 8, 4), 256, 0, stream>>>(t1, aowT, aob, aob, nullptr, hbuf,
        1024, 1024, 1024, 1024, m, m, 1024L, 0L, m, 0);
    // LSTM input projections, merged fwd|bwd: pre[e][tok][8192]
    gemm_bf16<1><<<dim3(64, 8, 4), 256, 0, stream>>>(hbuf, wiT, bfv, bbv, nullptr, pre,
        8192, 1024, 1024, 4096, m, 8 * m, 4096L, 0L, 8 * m, 0);
    // recurrence: one persistent kernel
    lstm_persistent<<<512, 512, 0, stream>>>(pre, whtf, whtb, hstate, memb, syncv);
    // gate branches: merged first layer (N=2048: sig|tan), out -> pre region
    unsigned short* g1o = pre;               // [E][1024][2048] bf16
    gemm_bf16<1><<<dim3(16, 8, 4), 256, 0, stream>>>(memb, gw1T, sb1, tb1, nullptr, g1o,
        2048, 2048, 2048, 1024, 2 * m, 4 * m, 1024L, 0L, 2 * m, 1);
    gemm_bf16<1><<<dim3(8, 8, 4), 256, 0, stream>>>(g1o, sw2T, sb2, sb2, nullptr, t2,
        1024, 1024, 2048, 1024, 2 * m, m, 1024L, 0L, m, 2);
    gemm_bf16<1><<<dim3(8, 8, 4), 256, 0, stream>>>(g1o + 1024, tw2T, tb2, tb2, t2, hbuf,
        1024, 1024, 2048, 1024, 2 * m, m, 1024L, m, m, 3);
    // decoder
    gemm_bf16<1><<<dim3(8, 8, 4), 256, 0, stream>>>(hbuf, dw1T, db1, db1, nullptr, t1,
        1024, 1024, 1024, 1024, m, m, 1024L, 0L, m, 1);
    gemm_bf16<0><<<dim3(4, 8, 4), 256, 0, stream>>>(t1, dw2T, db2, db2, nullptr, outs,
        512, 1024, 1024, 512, m, 512 * 1024L, 512L, 0L, 512 * 1024L, 0);
    ln_kernel<512><<<4096, 256, 0, stream>>>(outs, dg, dbeta);
    combine_kernel<<<512, 256, 0, stream>>>(outs, router, out);
}

// Round 8
// 1418.649 us; speedup vs baseline: 1.3276x; 1.3276x over previous
//
#include <hip/hip_runtime.h>

// B=8, S=128, IN=512, D=1024, E=4, NH=16, DH=64; tokens N=1024
// bf16 weights (transposed [N][K]) + MFMA 16x16x32; fp32 accumulate.
// LSTM: persistent kernel, Wh in regs. h exchange = sentinel-validated
// one-shot step buffers (bf16 0x7F7F sentinel; |h|<1 so never aliases).
// No fences, no tags, no barriers — data words self-validate.
// GEMM: double-buffered LDS with counted vmcnt (T3 2-phase).

typedef __attribute__((ext_vector_type(8))) short short8v;
typedef __attribute__((ext_vector_type(4))) float float4v;

__device__ __forceinline__ float bf2f(unsigned short u) {
    unsigned int x = ((unsigned int)u) << 16;
    return __builtin_bit_cast(float, x);
}
__device__ __forceinline__ unsigned short f2bf(float f) {
    unsigned int u = __builtin_bit_cast(unsigned int, f);
    u += 0x7fffu + ((u >> 16) & 1u);
    return (unsigned short)(u >> 16);
}
__device__ __forceinline__ void gload_lds16(const unsigned short* g, unsigned short* lds) {
    __builtin_amdgcn_global_load_lds(
        (const __attribute__((address_space(1))) unsigned int*)g,
        (__attribute__((address_space(3))) unsigned int*)lds, 16, 0, 0);
}
// inf-safe fast tanh: exact identity, __expf-based (library tanhf is slow)
__device__ __forceinline__ float ftanh(float x) {
    float e = __expf(2.f * x);
    return 1.f - 2.f / (e + 1.f);
}
// true iff any of the 4 bf16 in this 8B word is the 0x7f7f sentinel
__device__ __forceinline__ bool stale8(unsigned long long x) {
    unsigned lo = (unsigned)x, hi = (unsigned)(x >> 32);
    return ((lo & 0xffffu) == 0x7f7fu) | ((lo >> 16) == 0x7f7fu) |
           ((hi & 0xffffu) == 0x7f7fu) | ((hi >> 16) == 0x7f7fu);
}

// ---------------- fp32 -> bf16 elementwise convert -------------------------
__global__ __launch_bounds__(256) void cvt_bf16_kernel(
    const float* __restrict__ in, unsigned short* __restrict__ out, int n4)
{
    int i = blockIdx.x * 256 + threadIdx.x;
    if (i >= n4) return;
    float4 v = *reinterpret_cast<const float4*>(&in[i * 4]);
    ushort4 o;
    o.x = f2bf(v.x); o.y = f2bf(v.y); o.z = f2bf(v.z); o.w = f2bf(v.w);
    *reinterpret_cast<ushort4*>(&out[i * 4]) = o;
}

// ---------------- batched W[K][N] fp32 -> Wt[N][K] bf16 (all weights) ------
struct TransJobs {
    const float* src[14];
    unsigned short* dst[14];
    int K[14], N[14];
    int prefix[15];
    long sWe[14], sTe[14];
};

__global__ __launch_bounds__(256) void transpose_all(TransJobs J)
{
    __shared__ float tile[32][33];
    int bid = blockIdx.x;
    int j = 0;
    #pragma unroll
    for (int i = 0; i < 14; ++i) if (bid >= J.prefix[i + 1]) j = i + 1;
    int lb = bid - J.prefix[j];
    int K = J.K[j], N = J.N[j];
    int tn = N >> 5, tk = K >> 5;
    int e = lb / (tn * tk), rem = lb % (tn * tk);
    int ky = rem / tn, nx = rem % tn;
    const float* W = J.src[j] + (long)e * J.sWe[j];
    unsigned short* Wt = J.dst[j] + (long)e * J.sTe[j];
    int k0 = ky * 32, n0 = nx * 32;
    int tx = threadIdx.x & 31, ty = threadIdx.x >> 5;
    #pragma unroll
    for (int i = 0; i < 32; i += 8)
        tile[ty + i][tx] = W[(long)(k0 + ty + i) * N + n0 + tx];
    __syncthreads();
    #pragma unroll
    for (int i = 0; i < 32; i += 8)
        Wt[(long)(n0 + ty + i) * K + k0 + tx] = f2bf(tile[tx][ty + i]);
}

// ---------------- router (fp32) --------------------------------------------
__global__ __launch_bounds__(64) void router_kernel(
    const float* __restrict__ x, const float* __restrict__ rw,
    const float* __restrict__ rb, float* __restrict__ router)
{
    int token = blockIdx.x;
    int lane = threadIdx.x;
    float a0 = 0.f, a1 = 0.f, a2 = 0.f, a3 = 0.f;
    const float* xp = x + (long)token * 512;
    for (int i = lane; i < 512; i += 64) {
        float xv = xp[i];
        const float* w = rw + (long)i * 4;
        a0 += xv * w[0]; a1 += xv * w[1]; a2 += xv * w[2]; a3 += xv * w[3];
    }
    #pragma unroll
    for (int off = 32; off; off >>= 1) {
        a0 += __shfl_down(a0, off); a1 += __shfl_down(a1, off);
        a2 += __shfl_down(a2, off); a3 += __shfl_down(a3, off);
    }
    if (lane == 0) {
        a0 += rb[0]; a1 += rb[1]; a2 += rb[2]; a3 += rb[3];
        float m = fmaxf(fmaxf(a0, a1), fmaxf(a2, a3));
        float e0 = __expf(a0 - m), e1 = __expf(a1 - m);
        float e2 = __expf(a2 - m), e3 = __expf(a3 - m);
        float inv = 1.f / (e0 + e1 + e2 + e3);
        *reinterpret_cast<float4*>(&router[token * 4]) =
            make_float4(e0 * inv, e1 * inv, e2 * inv, e3 * inv);
    }
}

// ---------------- MFMA bf16 GEMM: C = act(A@W + bias) [*mul] ---------------
// Double-buffered LDS, counted vmcnt(8), loads in flight across barriers.
template <int OUTBF>
__global__ __launch_bounds__(256) void gemm_bf16(
    const unsigned short* __restrict__ A, const unsigned short* __restrict__ Wt,
    const float* __restrict__ bias, const float* __restrict__ bias2,
    const unsigned short* __restrict__ mul,
    void* __restrict__ Cv, int N, int K, int lda, int nsplit,
    long sAe, long sWe, long sBe, long sMe, long sCe, int act)
{
    __shared__ unsigned short As[2][128 * 64];
    __shared__ unsigned short Bs[2][128 * 64];
    int e = blockIdx.z;
    A += (long)e * sAe; Wt += (long)e * sWe;
    bias += (long)e * sBe; bias2 += (long)e * sBe;
    if (mul) mul += (long)e * sMe;
    int tid = threadIdx.x;
    int row0 = blockIdx.y * 128, col0 = blockIdx.x * 128;
    int wid = tid >> 6, lane = tid & 63;
    int wr = wid >> 1, wc = wid & 1;
    int l15 = lane & 15, l4 = lane >> 4;
    int r8 = lane >> 3, sg = lane & 7;
    float4v acc[4][4];
    #pragma unroll
    for (int i = 0; i < 4; ++i)
        #pragma unroll
        for (int j = 0; j < 4; ++j) acc[i][j] = (float4v){0.f, 0.f, 0.f, 0.f};

    auto STAGE = [&](int buf, int k0) {
        #pragma unroll
        for (int c = 0; c < 4; ++c) {
            int chunk = wid * 4 + c;
            int rowA = chunk * 8 + r8;
            int segA = (sg ^ (rowA & 7)) * 8;
            gload_lds16(A + (long)(row0 + rowA) * lda + k0 + segA,
                        (unsigned short*)((char*)As[buf] + chunk * 1024));
            gload_lds16(Wt + (long)(col0 + rowA) * K + k0 + segA,
                        (unsigned short*)((char*)Bs[buf] + chunk * 1024));
        }
    };
    int nt = K >> 6;
    STAGE(0, 0);
    for (int t = 0; t < nt; ++t) {
        int cur = t & 1;
        if (t + 1 < nt) {
            STAGE(cur ^ 1, (t + 1) << 6);
            asm volatile("s_waitcnt vmcnt(8)" ::: "memory");
        } else {
            asm volatile("s_waitcnt vmcnt(0)" ::: "memory");
        }
        __builtin_amdgcn_s_barrier();
        __builtin_amdgcn_sched_barrier(0);
        #pragma unroll
        for (int kk = 0; kk < 2; ++kk) {
            short8v af[4], bq[4];
            int bytec = kk * 64 + l4 * 16;
            #pragma unroll
            for (int m = 0; m < 4; ++m) {
                int r = wr * 64 + m * 16 + l15;
                af[m] = *reinterpret_cast<const short8v*>(
                    (char*)As[cur] + r * 128 + (bytec ^ ((r & 7) << 4)));
            }
            #pragma unroll
            for (int n = 0; n < 4; ++n) {
                int r = wc * 64 + n * 16 + l15;
                bq[n] = *reinterpret_cast<const short8v*>(
                    (char*)Bs[cur] + r * 128 + (bytec ^ ((r & 7) << 4)));
            }
            #pragma unroll
            for (int m = 0; m < 4; ++m)
                #pragma unroll
                for (int n = 0; n < 4; ++n)
                    acc[m][n] = __builtin_amdgcn_mfma_f32_16x16x32_bf16(
                        af[m], bq[n], acc[m][n], 0, 0, 0);
        }
        __builtin_amdgcn_sched_barrier(0);
        __builtin_amdgcn_s_barrier();
    }
    float* Cf = (float*)Cv + (long)e * sCe;
    unsigned short* Cb = (unsigned short*)Cv + (long)e * sCe;
    #pragma unroll
    for (int n = 0; n < 4; ++n) {
        int col = col0 + wc * 64 + n * 16 + l15;
        float bia = (col < nsplit) ? bias[col] : bias2[col - nsplit];
        #pragma unroll
        for (int m = 0; m < 4; ++m) {
            #pragma unroll
            for (int r = 0; r < 4; ++r) {
                long row = row0 + wr * 64 + m * 16 + l4 * 4 + r;
                float v = acc[m][n][r] + bia;
                if (act == 1) v = fmaxf(v, 0.f);
                else if (act == 2) v = 1.f / (1.f + __expf(-v));
                else if (act == 3) v = ftanh(v);
                if (mul) v *= bf2f(mul[row * N + col]);
                if (OUTBF) Cb[row * N + col] = f2bf(v);
                else       Cf[row * N + col] = v;
            }
        }
    }
}

// ---------------- LayerNorm bf16 in/out (DIM=1024) -------------------------
template <int DIM>
__global__ __launch_bounds__(256) void ln_bf16(
    unsigned short* __restrict__ buf, const float* __restrict__ g,
    const float* __restrict__ beta)
{
    constexpr int PT = DIM / 256;
    __shared__ float sbuf[4];
    int row = blockIdx.x, e = row >> 10;
    unsigned short* p = buf + (long)row * DIM;
    const float* gp = g + (long)e * DIM;
    const float* bp = beta + (long)e * DIM;
    int tid = threadIdx.x;
    float v[PT];
    ushort4 u = *reinterpret_cast<const ushort4*>(p + tid * PT);
    v[0] = bf2f(u.x); v[1] = bf2f(u.y); v[2] = bf2f(u.z); v[3] = bf2f(u.w);
    float s = v[0] + v[1] + v[2] + v[3];
    #pragma unroll
    for (int off = 32; off; off >>= 1) s += __shfl_down(s, off);
    if ((tid & 63) == 0) sbuf[tid >> 6] = s;
    __syncthreads();
    float mean = (sbuf[0] + sbuf[1] + sbuf[2] + sbuf[3]) / (float)DIM;
    __syncthreads();
    float vs = 0.f;
    #pragma unroll
    for (int i = 0; i < PT; ++i) { float d = v[i] - mean; vs += d * d; }
    #pragma unroll
    for (int off = 32; off; off >>= 1) vs += __shfl_down(vs, off);
    if ((tid & 63) == 0) sbuf[tid >> 6] = vs;
    __syncthreads();
    float var = (sbuf[0] + sbuf[1] + sbuf[2] + sbuf[3]) / (float)DIM;
    float rstd = rsqrtf(var + 1e-5f);
    ushort4 o;
    o.x = f2bf((v[0] - mean) * rstd * gp[tid * PT + 0] + bp[tid * PT + 0]);
    o.y = f2bf((v[1] - mean) * rstd * gp[tid * PT + 1] + bp[tid * PT + 1]);
    o.z = f2bf((v[2] - mean) * rstd * gp[tid * PT + 2] + bp[tid * PT + 2]);
    o.w = f2bf((v[3] - mean) * rstd * gp[tid * PT + 3] + bp[tid * PT + 3]);
    *reinterpret_cast<ushort4*>(p + tid * PT) = o;
}

// ---------------- LayerNorm fp32 in-place (DIM=512 final) ------------------
template <int DIM>
__global__ __launch_bounds__(256) void ln_kernel(
    float* __restrict__ buf, const float* __restrict__ g,
    const float* __restrict__ beta)
{
    constexpr int PT = DIM / 256;
    __shared__ float sbuf[4];
    int row = blockIdx.x, e = row >> 10;
    float* p = buf + (long)row * DIM;
    const float* gp = g + (long)e * DIM;
    const float* bp = beta + (long)e * DIM;
    int tid = threadIdx.x;
    float v[PT];
    float s = 0.f;
    #pragma unroll
    for (int i = 0; i < PT; ++i) { v[i] = p[tid + i * 256]; s += v[i]; }
    #pragma unroll
    for (int off = 32; off; off >>= 1) s += __shfl_down(s, off);
    if ((tid & 63) == 0) sbuf[tid >> 6] = s;
    __syncthreads();
    float mean = (sbuf[0] + sbuf[1] + sbuf[2] + sbuf[3]) / (float)DIM;
    __syncthreads();
    float vs = 0.f;
    #pragma unroll
    for (int i = 0; i < PT; ++i) { float d = v[i] - mean; vs += d * d; }
    #pragma unroll
    for (int off = 32; off; off >>= 1) vs += __shfl_down(vs, off);
    if ((tid & 63) == 0) sbuf[tid >> 6] = vs;
    __syncthreads();
    float var = (sbuf[0] + sbuf[1] + sbuf[2] + sbuf[3]) / (float)DIM;
    float rstd = rsqrtf(var + 1e-5f);
    #pragma unroll
    for (int i = 0; i < PT; ++i)
        p[tid + i * 256] = (v[i] - mean) * rstd * gp[tid + i * 256] + bp[tid + i * 256];
}

// ---------------- fused attention, bf16 in/out -----------------------------
__global__ __launch_bounds__(128) void attn_bf16(
    const unsigned short* __restrict__ qkv, unsigned short* __restrict__ o)
{
    __shared__ __align__(16) float Ks[128][64];
    __shared__ __align__(16) float Vs[128][64];
    int id = blockIdx.x;
    int hd = id & 15, b = (id >> 4) & 7, e = id >> 7;
    int tid = threadIdx.x;
    const long base = ((long)e * 1024 + b * 128) * 3072 + hd * 64;
    #pragma unroll
    for (int i = 0; i < 8; ++i) {
        int idx = i * 128 + tid;
        int row = idx >> 3, f8 = (idx & 7) * 8;
        short8v kv = *reinterpret_cast<const short8v*>(&qkv[base + (long)row * 3072 + 1024 + f8]);
        short8v vv = *reinterpret_cast<const short8v*>(&qkv[base + (long)row * 3072 + 2048 + f8]);
        #pragma unroll
        for (int j = 0; j < 8; ++j) {
            Ks[row][f8 + j] = bf2f((unsigned short)kv[j]);
            Vs[row][f8 + j] = bf2f((unsigned short)vv[j]);
        }
    }
    __syncthreads();
    float q[64];
    #pragma unroll
    for (int f = 0; f < 8; ++f) {
        short8v qv = *reinterpret_cast<const short8v*>(&qkv[base + (long)tid * 3072 + f * 8]);
        #pragma unroll
        for (int j = 0; j < 8; ++j) q[f * 8 + j] = bf2f((unsigned short)qv[j]);
    }
    float m = -__builtin_huge_valf(), l = 0.f;
    float oa[64];
    #pragma unroll
    for (int d = 0; d < 64; ++d) oa[d] = 0.f;
    for (int j = 0; j < 128; ++j) {
        float s = 0.f;
        #pragma unroll
        for (int d = 0; d < 64; ++d) s = fmaf(q[d], Ks[j][d], s);
        s *= 0.125f;
        float mn = fmaxf(m, s);
        float corr = __expf(m - mn);
        float pj = __expf(s - mn);
        l = l * corr + pj;
        #pragma unroll
        for (int d = 0; d < 64; ++d) oa[d] = oa[d] * corr + pj * Vs[j][d];
        m = mn;
    }
    float inv = 1.f / l;
    unsigned short* op = o + ((long)e * 1024 + b * 128 + tid) * 1024 + hd * 64;
    #pragma unroll
    for (int f = 0; f < 8; ++f) {
        short8v ov;
        #pragma unroll
        for (int j = 0; j < 8; ++j) ov[j] = (short)f2bf(oa[f * 8 + j] * inv);
        *reinterpret_cast<short8v*>(&op[f * 8]) = ov;
    }
}

// ---------------- persistent LSTM (sentinel one-shot buffers) --------------
// grid 512 x 512thr; chain ed = bid&7, cb = bid>>3 (16 h-cols each).
// hseq: bf16 [129 step][8 ed][8 b][1024]. Buffer 0 = zeros (h0); buffers
// 1..128 pre-filled with 0x7f7f sentinel each launch. Producer at step s
// writes buffer s+1 (4B atomic stores); consumers load buffer s and retry
// any 8B word still containing a sentinel bf16. |h|<1 => no aliasing.
__global__ __launch_bounds__(512, 4) void lstm_persistent(
    const unsigned short* __restrict__ pre, const unsigned short* __restrict__ whtf,
    const unsigned short* __restrict__ whtb, unsigned short* __restrict__ hseq,
    unsigned short* __restrict__ memb)
{
    __shared__ unsigned short hA[16 * 1024];       // 32KB swizzled A-operand
    __shared__ float zred[4][2][8][16];            // gate, khalf, batch, col
    int bid = blockIdx.x;
    int ed = bid & 7, cb = bid >> 3;
    int e = ed >> 1, dir = ed & 1;
    const unsigned short* Wt = (dir ? whtb : whtf) + (long)e * 4096 * 1024;
    int tid = threadIdx.x;
    int w = tid >> 6, lane = tid & 63, l15 = lane & 15, l4 = lane >> 4;
    int g = w >> 1, kh = w & 1;
    // one-time: weight fragments into registers
    short8v wf[16];
    const unsigned short* wp =
        Wt + ((long)(g * 1024 + cb * 16 + l15)) * 1024 + kh * 512 + l4 * 8;
    #pragma unroll
    for (int ks = 0; ks < 16; ++ks)
        wf[ks] = *reinterpret_cast<const short8v*>(wp + ks * 32);
    // one-time: zero pad rows 8..15 of hA
    short8v z8 = {0, 0, 0, 0, 0, 0, 0, 0};
    for (int i = tid; i < 8 * 128; i += 512) {
        int r = 8 + (i >> 7), sb = (i & 127) * 16;
        *reinterpret_cast<short8v*>((char*)hA + r * 2048 + (sb ^ ((r & 7) << 4))) = z8;
    }
    float c0 = 0.f, c1 = 0.f;                      // c-state (gate threads)
    int gp = tid & 7, gb = tid >> 3;               // gate mapping (tid<64)
    for (int s = 0; s < 128; ++s) {
        int t = dir ? 127 - s : s;
        const unsigned long long* hin64 = reinterpret_cast<const unsigned long long*>(
            hseq + ((long)s * 8 + ed) * 8192);
        __syncthreads();               // prev step's hA readers done
        // prefetch pre for gate threads (independent of h)
        float pz[8];
        if (tid < 64) {
            const unsigned short* prow =
                pre + (((long)e * 1024) + gb * 128 + t) * 8192 + dir * 4096 + cb * 16 + gp * 2;
            #pragma unroll
            for (int gg = 0; gg < 4; ++gg) {
                unsigned int u = *reinterpret_cast<const unsigned int*>(prow + gg * 1024);
                pz[gg * 2]     = bf2f((unsigned short)(u & 0xffff));
                pz[gg * 2 + 1] = bf2f((unsigned short)(u >> 16));
            }
        }
        // load h(s-1) with sentinel validation (4 x 8B per thread)
        unsigned long long v[4];
        #pragma unroll
        for (int i = 0; i < 4; ++i)
            v[i] = __hip_atomic_load(hin64 + tid + 512 * i,
                                     __ATOMIC_RELAXED, __HIP_MEMORY_SCOPE_AGENT);
        unsigned pend = 0xfu;
        while (true) {
            unsigned np = 0;
            #pragma unroll
            for (int i = 0; i < 4; ++i)
                if ((pend >> i) & 1u)
                    if (stale8(v[i])) np |= 1u << i;
            if (!np) break;
            __builtin_amdgcn_s_sleep(1);
            #pragma unroll
            for (int i = 0; i < 4; ++i)
                if ((np >> i) & 1u)
                    v[i] = __hip_atomic_load(hin64 + tid + 512 * i,
                                             __ATOMIC_RELAXED, __HIP_MEMORY_SCOPE_AGENT);
            pend = np;
        }
        // write swizzled LDS
        #pragma unroll
        for (int i = 0; i < 4; ++i) {
            int idx = tid + 512 * i;               // 0..2047 (8B units)
            int r = idx >> 8, sb = (idx & 255) * 8;
            *reinterpret_cast<unsigned long long*>(
                (char*)hA + r * 2048 + (sb ^ ((r & 7) << 4))) = v[i];
        }
        __syncthreads();
        // MFMA: acc = h @ Wh[:, mycols]
        float4v acc = (float4v){0.f, 0.f, 0.f, 0.f};
        int abase = l15 * 2048, aswz = (l15 & 7) << 4;
        #pragma unroll
        for (int ks = 0; ks < 16; ++ks) {
            short8v a = *reinterpret_cast<const short8v*>(
                (char*)hA + abase + (((kh * 512 + ks * 32) * 2 + l4 * 16) ^ aswz));
            acc = __builtin_amdgcn_mfma_f32_16x16x32_bf16(a, wf[ks], acc, 0, 0, 0);
        }
        if (l4 < 2) {
            #pragma unroll
            for (int r = 0; r < 4; ++r)
                zred[g][kh][l4 * 4 + r][l15] = acc[r];
        }
        __syncthreads();
        if (tid < 64) {
            int col0 = gp * 2;
            float h2[2];
            #pragma unroll
            for (int cc = 0; cc < 2; ++cc) {
                int col = col0 + cc;
                float zi = zred[0][0][gb][col] + zred[0][1][gb][col] + pz[0 + cc];
                float zf = zred[1][0][gb][col] + zred[1][1][gb][col] + pz[2 + cc];
                float zg = zred[2][0][gb][col] + zred[2][1][gb][col] + pz[4 + cc];
                float zo = zred[3][0][gb][col] + zred[3][1][gb][col] + pz[6 + cc];
                float ig = 1.f / (1.f + __expf(-zi));
                float fg = 1.f / (1.f + __expf(-zf));
                float gv = ftanh(zg);
                float og = 1.f / (1.f + __expf(-zo));
                float cv = cc ? c1 : c0;
                cv = fg * cv + ig * gv;
                if (cc) c1 = cv; else c0 = cv;
                h2[cc] = og * ftanh(cv);
            }
            unsigned int hv = (unsigned int)f2bf(h2[0]) | ((unsigned int)f2bf(h2[1]) << 16);
            int hcol = cb * 16 + col0;
            unsigned int* hout32 = reinterpret_cast<unsigned int*>(
                hseq + ((long)(s + 1) * 8 + ed) * 8192);
            __hip_atomic_store(hout32 + (gb * 1024 + hcol) / 2, hv,
                               __ATOMIC_RELAXED, __HIP_MEMORY_SCOPE_AGENT);
            *reinterpret_cast<unsigned int*>(
                memb + (((long)e * 8 + gb) * 128 + t) * 2048 + dir * 1024 + hcol) = hv;
        }
        // no barrier: sentinel-validated data synchronizes the next step
    }
}

// ---------------- routed combine (fp32) ------------------------------------
__global__ __launch_bounds__(256) void combine_kernel(
    const float* __restrict__ outs, const float* __restrict__ router,
    float* __restrict__ out)
{
    int idx = blockIdx.x * 256 + threadIdx.x;
    int token = idx >> 7, q = (idx & 127) * 4;
    float4 r = *reinterpret_cast<const float4*>(&router[token * 4]);
    const float* bp = outs + (long)token * 512 + q;
    float4 v0 = *reinterpret_cast<const float4*>(bp);
    float4 v1 = *reinterpret_cast<const float4*>(bp + 524288);
    float4 v2 = *reinterpret_cast<const float4*>(bp + 1048576);
    float4 v3 = *reinterpret_cast<const float4*>(bp + 1572864);
    float4 a;
    a.x = r.x * v0.x + r.y * v1.x + r.z * v2.x + r.w * v3.x;
    a.y = r.x * v0.y + r.y * v1.y + r.z * v2.y + r.w * v3.y;
    a.z = r.x * v0.z + r.y * v1.z + r.z * v2.z + r.w * v3.z;
    a.w = r.x * v0.w + r.y * v1.w + r.z * v2.w + r.w * v3.w;
    *reinterpret_cast<float4*>(&out[(long)token * 512 + q]) = a;
}

extern "C" void kernel_launch(void* const* d_in, const int* in_sizes, int n_in,
                              void* d_out, int out_size, void* d_ws, size_t ws_size,
                              hipStream_t stream)
{
    (void)in_sizes; (void)n_in; (void)out_size; (void)ws_size;
    const float* x        = (const float*)d_in[0];
    const float* router_w = (const float*)d_in[1];
    const float* router_b = (const float*)d_in[2];
    const float* enc_w1   = (const float*)d_in[3];
    const float* enc_b1   = (const float*)d_in[4];
    const float* enc_w2   = (const float*)d_in[5];
    const float* enc_b2   = (const float*)d_in[6];
    const float* enc_g    = (const float*)d_in[7];
    const float* enc_beta = (const float*)d_in[8];
    const float* aiw      = (const float*)d_in[9];
    const float* aib      = (const float*)d_in[10];
    const float* aow      = (const float*)d_in[11];
    const float* aob      = (const float*)d_in[12];
    const float* wif      = (const float*)d_in[13];
    const float* whf      = (const float*)d_in[14];
    const float* bfv      = (const float*)d_in[15];
    const float* wib      = (const float*)d_in[16];
    const float* whb      = (const float*)d_in[17];
    const float* bbv      = (const float*)d_in[18];
    const float* sw1      = (const float*)d_in[19];
    const float* sb1      = (const float*)d_in[20];
    const float* sw2      = (const float*)d_in[21];
    const float* sb2      = (const float*)d_in[22];
    const float* tw1      = (const float*)d_in[23];
    const float* tb1      = (const float*)d_in[24];
    const float* tw2      = (const float*)d_in[25];
    const float* tb2      = (const float*)d_in[26];
    const float* dw1      = (const float*)d_in[27];
    const float* db1      = (const float*)d_in[28];
    const float* dw2      = (const float*)d_in[29];
    const float* db2      = (const float*)d_in[30];
    const float* dg       = (const float*)d_in[31];
    const float* dbeta    = (const float*)d_in[32];
    float* out = (float*)d_out;

    const long m = 1024L * 1024L;
    unsigned short* U = (unsigned short*)d_ws;
    unsigned short* ew1T = U;               // 2m
    unsigned short* ew2T = U + 2 * m;       // 4m
    unsigned short* aiwT = U + 6 * m;       // 12m
    unsigned short* aowT = U + 18 * m;      // 4m
    unsigned short* wiT  = U + 22 * m;      // 32m: [e][fwd4096|bwd4096][1024]
    unsigned short* whtf = U + 54 * m;      // 16m
    unsigned short* whtb = U + 70 * m;      // 16m
    unsigned short* gw1T = U + 86 * m;      // 16m: per-e 4m slab (sw1|tw1 cols)
    unsigned short* sw2T = U + 102 * m;     // 4m
    unsigned short* tw2T = U + 106 * m;     // 4m
    unsigned short* dw1T = U + 110 * m;     // 4m
    unsigned short* dw2T = U + 114 * m;     // 2m
    unsigned short* xb   = U + 116 * m;     // 0.5m
    unsigned short* hbuf = xb + 524288;     // 4m
    unsigned short* t1   = hbuf + 4 * m;    // 4m
    unsigned short* t2   = t1 + 4 * m;      // 4m
    unsigned short* pre  = t2 + 4 * m;      // 32m (early: qkv; late: gate1 out)
    unsigned short* memb = pre + 32 * m;    // 8m
    float* F      = (float*)(U + 170 * m);
    float* outs   = F;                      // 2m floats
    float* router = outs + 2 * m;           // 4096
    // hseq REUSES the encoder/attention weight-transpose region [0..22m):
    // ew1T/ew2T/aiwT are fully consumed before the LSTM; the sentinel
    // memsets below run after their last reader (stream-ordered), and
    // transpose_all rewrites the region on every launch (deterministic).
    unsigned short* hseq = U;               // [129][8][8192] bf16 = 16.9 MB

    // one-time conversions: x + all weights (one batched dispatch)
    cvt_bf16_kernel<<<512, 256, 0, stream>>>(x, xb, 131072);
    {
        TransJobs J;
        const float* srcs[14] = {enc_w1, enc_w2, aiw, aow, wif, wib, whf, whb,
                                 sw1, tw1, sw2, tw2, dw1, dw2};
        unsigned short* dsts[14] = {ew1T, ew2T, aiwT, aowT, wiT, wiT + 4096 * 1024L,
                                    whtf, whtb, gw1T, gw1T + 2 * m, sw2T, tw2T, dw1T, dw2T};
        int Ks[14] = {512, 1024, 1024, 1024, 1024, 1024, 1024, 1024,
                      2048, 2048, 1024, 1024, 1024, 1024};
        int Ns[14] = {1024, 1024, 3072, 1024, 4096, 4096, 4096, 4096,
                      1024, 1024, 1024, 1024, 1024, 512};
        long sWes[14] = {512 * 1024L, m, 3 * m, m, 4 * m, 4 * m, 4 * m, 4 * m,
                         2 * m, 2 * m, m, m, m, 512 * 1024L};
        long sTes[14] = {512 * 1024L, m, 3 * m, m, 8 * m, 8 * m, 4 * m, 4 * m,
                         4 * m, 4 * m, m, m, m, 512 * 1024L};
        int pfx = 0;
        J.prefix[0] = 0;
        for (int i = 0; i < 14; ++i) {
            J.src[i] = srcs[i]; J.dst[i] = dsts[i];
            J.K[i] = Ks[i]; J.N[i] = Ns[i];
            J.sWe[i] = sWes[i]; J.sTe[i] = sTes[i];
            pfx += (Ns[i] >> 5) * (Ks[i] >> 5) * 4;
            J.prefix[i + 1] = pfx;
        }
        transpose_all<<<pfx, 256, 0, stream>>>(J);
    }

    router_kernel<<<1024, 64, 0, stream>>>(x, router_w, router_b, router);

    // encoder
    gemm_bf16<1><<<dim3(8, 8, 4), 256, 0, stream>>>(xb, ew1T, enc_b1, enc_b1, nullptr, t1,
        1024, 512, 512, 1024, 0L, 512 * 1024L, 1024L, 0L, m, 1);
    gemm_bf16<1><<<dim3(8, 8, 4), 256, 0, stream>>>(t1, ew2T, enc_b2, enc_b2, nullptr, hbuf,
        1024, 1024, 1024, 1024, m, m, 1024L, 0L, m, 0);
    ln_bf16<1024><<<4096, 256, 0, stream>>>(hbuf, enc_g, enc_beta);
    // attention (qkv in pre region)
    gemm_bf16<1><<<dim3(24, 8, 4), 256, 0, stream>>>(hbuf, aiwT, aib, aib, nullptr, pre,
        3072, 1024, 1024, 3072, m, 3 * m, 3072L, 0L, 3 * m, 0);
    attn_bf16<<<512, 128, 0, stream>>>(pre, t1);
    gemm_bf16<1><<<dim3(8, 8, 4), 256, 0, stream>>>(t1, aowT, aob, aob, nullptr, hbuf,
        1024, 1024, 1024, 1024, m, m, 1024L, 0L, m, 0);
    // LSTM input projections, merged fwd|bwd: pre[e][tok][8192]
    gemm_bf16<1><<<dim3(64, 8, 4), 256, 0, stream>>>(hbuf, wiT, bfv, bbv, nullptr, pre,
        8192, 1024, 1024, 4096, m, 8 * m, 4096L, 0L, 8 * m, 0);
    // hseq init: step-0 slab = zeros (h0), steps 1..128 = 0x7f7f sentinel.
    // Runs after every reader of the reused region (stream-ordered).
    hipMemsetAsync(hseq, 0, 8 * 8192 * sizeof(unsigned short), stream);
    hipMemsetAsync(hseq + 8 * 8192, 0x7f,
                   128L * 8 * 8192 * sizeof(unsigned short), stream);
    // recurrence: one persistent kernel, barrier-free
    lstm_persistent<<<512, 512, 0, stream>>>(pre, whtf, whtb, hseq, memb);
    // gate branches: merged first layer (N=2048: sig|tan), out -> pre region
    unsigned short* g1o = pre;               // [E][1024][2048] bf16
    gemm_bf16<1><<<dim3(16, 8, 4), 256, 0, stream>>>(memb, gw1T, sb1, tb1, nullptr, g1o,
        2048, 2048, 2048, 1024, 2 * m, 4 * m, 1024L, 0L, 2 * m, 1);
    gemm_bf16<1><<<dim3(8, 8, 4), 256, 0, stream>>>(g1o, sw2T, sb2, sb2, nullptr, t2,
        1024, 1024, 2048, 1024, 2 * m, m, 1024L, 0L, m, 2);
    gemm_bf16<1><<<dim3(8, 8, 4), 256, 0, stream>>>(g1o + 1024, tw2T, tb2, tb2, t2, hbuf,
        1024, 1024, 2048, 1024, 2 * m, m, 1024L, m, m, 3);
    // decoder
    gemm_bf16<1><<<dim3(8, 8, 4), 256, 0, stream>>>(hbuf, dw1T, db1, db1, nullptr, t1,
        1024, 1024, 1024, 1024, m, m, 1024L, 0L, m, 1);
    gemm_bf16<0><<<dim3(4, 8, 4), 256, 0, stream>>>(t1, dw2T, db2, db2, nullptr, outs,
        512, 1024, 1024, 512, m, 512 * 1024L, 512L, 0L, 512 * 1024L, 0);
    ln_kernel<512><<<4096, 256, 0, stream>>>(outs, dg, dbeta);
    combine_kernel<<<512, 256, 0, stream>>>(outs, router, out);
}

// Round 9
// 1383.007 us; speedup vs baseline: 1.3618x; 1.0258x over previous
//
#include <hip/hip_runtime.h>

// B=8, S=128, IN=512, D=1024, E=4, NH=16, DH=64; tokens N=1024
// bf16 weights (transposed [N][K]) + MFMA 16x16x32; fp32 accumulate.
// LSTM: persistent kernel (round-5 tag scheme), wave-local drain+signal.
// GEMM: 512-thread / 8-wave blocks, double-buffered LDS, counted vmcnt(4).

typedef __attribute__((ext_vector_type(8))) short short8v;
typedef __attribute__((ext_vector_type(4))) float float4v;

__device__ __forceinline__ float bf2f(unsigned short u) {
    unsigned int x = ((unsigned int)u) << 16;
    return __builtin_bit_cast(float, x);
}
__device__ __forceinline__ unsigned short f2bf(float f) {
    unsigned int u = __builtin_bit_cast(unsigned int, f);
    u += 0x7fffu + ((u >> 16) & 1u);
    return (unsigned short)(u >> 16);
}
__device__ __forceinline__ void gload_lds16(const unsigned short* g, unsigned short* lds) {
    __builtin_amdgcn_global_load_lds(
        (const __attribute__((address_space(1))) unsigned int*)g,
        (__attribute__((address_space(3))) unsigned int*)lds, 16, 0, 0);
}
// inf-safe fast tanh via __expf (library tanhf is slow; exact identity)
__device__ __forceinline__ float ftanh(float x) {
    float e = __expf(2.f * x);
    return 1.f - 2.f / (e + 1.f);
}

// ---------------- fp32 -> bf16 elementwise convert -------------------------
__global__ __launch_bounds__(256) void cvt_bf16_kernel(
    const float* __restrict__ in, unsigned short* __restrict__ out, int n4)
{
    int i = blockIdx.x * 256 + threadIdx.x;
    if (i >= n4) return;
    float4 v = *reinterpret_cast<const float4*>(&in[i * 4]);
    ushort4 o;
    o.x = f2bf(v.x); o.y = f2bf(v.y); o.z = f2bf(v.z); o.w = f2bf(v.w);
    *reinterpret_cast<ushort4*>(&out[i * 4]) = o;
}

// ---------------- batched W[K][N] fp32 -> Wt[N][K] bf16 (all weights) ------
struct TransJobs {
    const float* src[14];
    unsigned short* dst[14];
    int K[14], N[14];
    int prefix[15];
    long sWe[14], sTe[14];
};

__global__ __launch_bounds__(256) void transpose_all(TransJobs J)
{
    __shared__ float tile[32][33];
    int bid = blockIdx.x;
    int j = 0;
    #pragma unroll
    for (int i = 0; i < 14; ++i) if (bid >= J.prefix[i + 1]) j = i + 1;
    int lb = bid - J.prefix[j];
    int K = J.K[j], N = J.N[j];
    int tn = N >> 5, tk = K >> 5;
    int e = lb / (tn * tk), rem = lb % (tn * tk);
    int ky = rem / tn, nx = rem % tn;
    const float* W = J.src[j] + (long)e * J.sWe[j];
    unsigned short* Wt = J.dst[j] + (long)e * J.sTe[j];
    int k0 = ky * 32, n0 = nx * 32;
    int tx = threadIdx.x & 31, ty = threadIdx.x >> 5;
    #pragma unroll
    for (int i = 0; i < 32; i += 8)
        tile[ty + i][tx] = W[(long)(k0 + ty + i) * N + n0 + tx];
    __syncthreads();
    #pragma unroll
    for (int i = 0; i < 32; i += 8)
        Wt[(long)(n0 + ty + i) * K + k0 + tx] = f2bf(tile[tx][ty + i]);
}

// ---------------- router (fp32) --------------------------------------------
__global__ __launch_bounds__(64) void router_kernel(
    const float* __restrict__ x, const float* __restrict__ rw,
    const float* __restrict__ rb, float* __restrict__ router)
{
    int token = blockIdx.x;
    int lane = threadIdx.x;
    float a0 = 0.f, a1 = 0.f, a2 = 0.f, a3 = 0.f;
    const float* xp = x + (long)token * 512;
    for (int i = lane; i < 512; i += 64) {
        float xv = xp[i];
        const float* w = rw + (long)i * 4;
        a0 += xv * w[0]; a1 += xv * w[1]; a2 += xv * w[2]; a3 += xv * w[3];
    }
    #pragma unroll
    for (int off = 32; off; off >>= 1) {
        a0 += __shfl_down(a0, off); a1 += __shfl_down(a1, off);
        a2 += __shfl_down(a2, off); a3 += __shfl_down(a3, off);
    }
    if (lane == 0) {
        a0 += rb[0]; a1 += rb[1]; a2 += rb[2]; a3 += rb[3];
        float m = fmaxf(fmaxf(a0, a1), fmaxf(a2, a3));
        float e0 = __expf(a0 - m), e1 = __expf(a1 - m);
        float e2 = __expf(a2 - m), e3 = __expf(a3 - m);
        float inv = 1.f / (e0 + e1 + e2 + e3);
        *reinterpret_cast<float4*>(&router[token * 4]) =
            make_float4(e0 * inv, e1 * inv, e2 * inv, e3 * inv);
    }
}

// ---------------- MFMA bf16 GEMM: C = act(A@W + bias) [*mul] ---------------
// 512 threads / 8 waves: wave w -> rows [wr*64,+64), cols [wc*32,+32).
// Double-buffered LDS, counted vmcnt(4), loads in flight across barriers.
template <int OUTBF>
__global__ __launch_bounds__(512) void gemm_bf16(
    const unsigned short* __restrict__ A, const unsigned short* __restrict__ Wt,
    const float* __restrict__ bias, const float* __restrict__ bias2,
    const unsigned short* __restrict__ mul,
    void* __restrict__ Cv, int N, int K, int lda, int nsplit,
    long sAe, long sWe, long sBe, long sMe, long sCe, int act)
{
    __shared__ unsigned short As[2][128 * 64];
    __shared__ unsigned short Bs[2][128 * 64];
    int e = blockIdx.z;
    A += (long)e * sAe; Wt += (long)e * sWe;
    bias += (long)e * sBe; bias2 += (long)e * sBe;
    if (mul) mul += (long)e * sMe;
    int tid = threadIdx.x;
    int row0 = blockIdx.y * 128, col0 = blockIdx.x * 128;
    int wid = tid >> 6, lane = tid & 63;
    int wr = wid >> 2, wc = wid & 3;
    int l15 = lane & 15, l4 = lane >> 4;
    int r8 = lane >> 3, sg = lane & 7;
    float4v acc[4][2];
    #pragma unroll
    for (int i = 0; i < 4; ++i)
        #pragma unroll
        for (int j = 0; j < 2; ++j) acc[i][j] = (float4v){0.f, 0.f, 0.f, 0.f};

    auto STAGE = [&](int buf, int k0) {
        #pragma unroll
        for (int c = 0; c < 2; ++c) {
            int chunk = wid * 2 + c;                  // 0..15
            int rowA = chunk * 8 + r8;
            int segA = (sg ^ (rowA & 7)) * 8;
            gload_lds16(A + (long)(row0 + rowA) * lda + k0 + segA,
                        (unsigned short*)((char*)As[buf] + chunk * 1024));
            gload_lds16(Wt + (long)(col0 + rowA) * K + k0 + segA,
                        (unsigned short*)((char*)Bs[buf] + chunk * 1024));
        }
    };
    int nt = K >> 6;
    STAGE(0, 0);
    for (int t = 0; t < nt; ++t) {
        int cur = t & 1;
        if (t + 1 < nt) {
            STAGE(cur ^ 1, (t + 1) << 6);
            asm volatile("s_waitcnt vmcnt(4)" ::: "memory");
        } else {
            asm volatile("s_waitcnt vmcnt(0)" ::: "memory");
        }
        __builtin_amdgcn_s_barrier();
        __builtin_amdgcn_sched_barrier(0);
        #pragma unroll
        for (int kk = 0; kk < 2; ++kk) {
            short8v af[4], bq[2];
            int bytec = kk * 64 + l4 * 16;
            #pragma unroll
            for (int m = 0; m < 4; ++m) {
                int r = wr * 64 + m * 16 + l15;
                af[m] = *reinterpret_cast<const short8v*>(
                    (char*)As[cur] + r * 128 + (bytec ^ ((r & 7) << 4)));
            }
            #pragma unroll
            for (int n = 0; n < 2; ++n) {
                int r = wc * 32 + n * 16 + l15;
                bq[n] = *reinterpret_cast<const short8v*>(
                    (char*)Bs[cur] + r * 128 + (bytec ^ ((r & 7) << 4)));
            }
            #pragma unroll
            for (int m = 0; m < 4; ++m)
                #pragma unroll
                for (int n = 0; n < 2; ++n)
                    acc[m][n] = __builtin_amdgcn_mfma_f32_16x16x32_bf16(
                        af[m], bq[n], acc[m][n], 0, 0, 0);
        }
        __builtin_amdgcn_sched_barrier(0);
        __builtin_amdgcn_s_barrier();
    }
    float* Cf = (float*)Cv + (long)e * sCe;
    unsigned short* Cb = (unsigned short*)Cv + (long)e * sCe;
    #pragma unroll
    for (int n = 0; n < 2; ++n) {
        int col = col0 + wc * 32 + n * 16 + l15;
        float bia = (col < nsplit) ? bias[col] : bias2[col - nsplit];
        #pragma unroll
        for (int m = 0; m < 4; ++m) {
            #pragma unroll
            for (int r = 0; r < 4; ++r) {
                long row = row0 + wr * 64 + m * 16 + l4 * 4 + r;
                float v = acc[m][n][r] + bia;
                if (act == 1) v = fmaxf(v, 0.f);
                else if (act == 2) v = 1.f / (1.f + __expf(-v));
                else if (act == 3) v = ftanh(v);
                if (mul) v *= bf2f(mul[row * N + col]);
                if (OUTBF) Cb[row * N + col] = f2bf(v);
                else       Cf[row * N + col] = v;
            }
        }
    }
}

// ---------------- LayerNorm bf16 in/out (DIM=1024) -------------------------
template <int DIM>
__global__ __launch_bounds__(256) void ln_bf16(
    unsigned short* __restrict__ buf, const float* __restrict__ g,
    const float* __restrict__ beta)
{
    constexpr int PT = DIM / 256;
    __shared__ float sbuf[4];
    int row = blockIdx.x, e = row >> 10;
    unsigned short* p = buf + (long)row * DIM;
    const float* gp = g + (long)e * DIM;
    const float* bp = beta + (long)e * DIM;
    int tid = threadIdx.x;
    float v[PT];
    ushort4 u = *reinterpret_cast<const ushort4*>(p + tid * PT);
    v[0] = bf2f(u.x); v[1] = bf2f(u.y); v[2] = bf2f(u.z); v[3] = bf2f(u.w);
    float s = v[0] + v[1] + v[2] + v[3];
    #pragma unroll
    for (int off = 32; off; off >>= 1) s += __shfl_down(s, off);
    if ((tid & 63) == 0) sbuf[tid >> 6] = s;
    __syncthreads();
    float mean = (sbuf[0] + sbuf[1] + sbuf[2] + sbuf[3]) / (float)DIM;
    __syncthreads();
    float vs = 0.f;
    #pragma unroll
    for (int i = 0; i < PT; ++i) { float d = v[i] - mean; vs += d * d; }
    #pragma unroll
    for (int off = 32; off; off >>= 1) vs += __shfl_down(vs, off);
    if ((tid & 63) == 0) sbuf[tid >> 6] = vs;
    __syncthreads();
    float var = (sbuf[0] + sbuf[1] + sbuf[2] + sbuf[3]) / (float)DIM;
    float rstd = rsqrtf(var + 1e-5f);
    ushort4 o;
    o.x = f2bf((v[0] - mean) * rstd * gp[tid * PT + 0] + bp[tid * PT + 0]);
    o.y = f2bf((v[1] - mean) * rstd * gp[tid * PT + 1] + bp[tid * PT + 1]);
    o.z = f2bf((v[2] - mean) * rstd * gp[tid * PT + 2] + bp[tid * PT + 2]);
    o.w = f2bf((v[3] - mean) * rstd * gp[tid * PT + 3] + bp[tid * PT + 3]);
    *reinterpret_cast<ushort4*>(p + tid * PT) = o;
}

// ---------------- LayerNorm fp32 in-place (DIM=512 final) ------------------
template <int DIM>
__global__ __launch_bounds__(256) void ln_kernel(
    float* __restrict__ buf, const float* __restrict__ g,
    const float* __restrict__ beta)
{
    constexpr int PT = DIM / 256;
    __shared__ float sbuf[4];
    int row = blockIdx.x, e = row >> 10;
    float* p = buf + (long)row * DIM;
    const float* gp = g + (long)e * DIM;
    const float* bp = beta + (long)e * DIM;
    int tid = threadIdx.x;
    float v[PT];
    float s = 0.f;
    #pragma unroll
    for (int i = 0; i < PT; ++i) { v[i] = p[tid + i * 256]; s += v[i]; }
    #pragma unroll
    for (int off = 32; off; off >>= 1) s += __shfl_down(s, off);
    if ((tid & 63) == 0) sbuf[tid >> 6] = s;
    __syncthreads();
    float mean = (sbuf[0] + sbuf[1] + sbuf[2] + sbuf[3]) / (float)DIM;
    __syncthreads();
    float vs = 0.f;
    #pragma unroll
    for (int i = 0; i < PT; ++i) { float d = v[i] - mean; vs += d * d; }
    #pragma unroll
    for (int off = 32; off; off >>= 1) vs += __shfl_down(vs, off);
    if ((tid & 63) == 0) sbuf[tid >> 6] = vs;
    __syncthreads();
    float var = (sbuf[0] + sbuf[1] + sbuf[2] + sbuf[3]) / (float)DIM;
    float rstd = rsqrtf(var + 1e-5f);
    #pragma unroll
    for (int i = 0; i < PT; ++i)
        p[tid + i * 256] = (v[i] - mean) * rstd * gp[tid + i * 256] + bp[tid + i * 256];
}

// ---------------- fused attention, bf16 in/out -----------------------------
__global__ __launch_bounds__(128) void attn_bf16(
    const unsigned short* __restrict__ qkv, unsigned short* __restrict__ o)
{
    __shared__ __align__(16) float Ks[128][64];
    __shared__ __align__(16) float Vs[128][64];
    int id = blockIdx.x;
    int hd = id & 15, b = (id >> 4) & 7, e = id >> 7;
    int tid = threadIdx.x;
    const long base = ((long)e * 1024 + b * 128) * 3072 + hd * 64;
    #pragma unroll
    for (int i = 0; i < 8; ++i) {
        int idx = i * 128 + tid;
        int row = idx >> 3, f8 = (idx & 7) * 8;
        short8v kv = *reinterpret_cast<const short8v*>(&qkv[base + (long)row * 3072 + 1024 + f8]);
        short8v vv = *reinterpret_cast<const short8v*>(&qkv[base + (long)row * 3072 + 2048 + f8]);
        #pragma unroll
        for (int j = 0; j < 8; ++j) {
            Ks[row][f8 + j] = bf2f((unsigned short)kv[j]);
            Vs[row][f8 + j] = bf2f((unsigned short)vv[j]);
        }
    }
    __syncthreads();
    float q[64];
    #pragma unroll
    for (int f = 0; f < 8; ++f) {
        short8v qv = *reinterpret_cast<const short8v*>(&qkv[base + (long)tid * 3072 + f * 8]);
        #pragma unroll
        for (int j = 0; j < 8; ++j) q[f * 8 + j] = bf2f((unsigned short)qv[j]);
    }
    float m = -__builtin_huge_valf(), l = 0.f;
    float oa[64];
    #pragma unroll
    for (int d = 0; d < 64; ++d) oa[d] = 0.f;
    for (int j = 0; j < 128; ++j) {
        float s = 0.f;
        #pragma unroll
        for (int d = 0; d < 64; ++d) s = fmaf(q[d], Ks[j][d], s);
        s *= 0.125f;
        float mn = fmaxf(m, s);
        float corr = __expf(m - mn);
        float pj = __expf(s - mn);
        l = l * corr + pj;
        #pragma unroll
        for (int d = 0; d < 64; ++d) oa[d] = oa[d] * corr + pj * Vs[j][d];
        m = mn;
    }
    float inv = 1.f / l;
    unsigned short* op = o + ((long)e * 1024 + b * 128 + tid) * 1024 + hd * 64;
    #pragma unroll
    for (int f = 0; f < 8; ++f) {
        short8v ov;
        #pragma unroll
        for (int j = 0; j < 8; ++j) ov[j] = (short)f2bf(oa[f * 8 + j] * inv);
        *reinterpret_cast<short8v*>(&op[f * 8]) = ov;
    }
}

// ---------------- persistent LSTM ------------------------------------------
// grid 512 x 512thr; chain ed = bid&7, cb = bid>>3 (16 h-cols each).
// h exchange: relaxed agent-scope atomics; barrier: single-hop all-to-all
// monotonic tags. Signal path is WAVE-LOCAL: only wave 0 (gate threads)
// drains its own h-stores (s_waitcnt vmcnt(0)), signals, and polls; waves
// 1..7 proceed to the top-of-loop __syncthreads which releases them.
__global__ __launch_bounds__(512, 4) void lstm_persistent(
    const unsigned short* __restrict__ pre, const unsigned short* __restrict__ whtf,
    const unsigned short* __restrict__ whtb, unsigned short* __restrict__ hstate,
    unsigned short* __restrict__ memb, unsigned int* __restrict__ sync)
{
    __shared__ unsigned short hA[16 * 1024];       // 32KB swizzled A-operand
    __shared__ float zred[4][2][8][16];            // gate, khalf, batch, col
    int bid = blockIdx.x;
    int ed = bid & 7, cb = bid >> 3;
    int e = ed >> 1, dir = ed & 1;
    const unsigned short* Wt = (dir ? whtb : whtf) + (long)e * 4096 * 1024;
    unsigned int* arr = sync + ed * 64;            // [8][64] arrival slots
    int tid = threadIdx.x;
    int w = tid >> 6, lane = tid & 63, l15 = lane & 15, l4 = lane >> 4;
    int g = w >> 1, kh = w & 1;
    // one-time: weight fragments into registers
    short8v wf[16];
    const unsigned short* wp =
        Wt + ((long)(g * 1024 + cb * 16 + l15)) * 1024 + kh * 512 + l4 * 8;
    #pragma unroll
    for (int ks = 0; ks < 16; ++ks)
        wf[ks] = *reinterpret_cast<const short8v*>(wp + ks * 32);
    // one-time: zero pad rows 8..15 of hA
    short8v z8 = {0, 0, 0, 0, 0, 0, 0, 0};
    for (int i = tid; i < 8 * 128; i += 512) {
        int r = 8 + (i >> 7), sb = (i & 127) * 16;
        *reinterpret_cast<short8v*>((char*)hA + r * 2048 + (sb ^ ((r & 7) << 4))) = z8;
    }
    float c0 = 0.f, c1 = 0.f;                      // c-state (gate threads)
    int gp = tid & 7, gb = tid >> 3;               // gate mapping (tid<64)
    for (int s = 0; s < 128; ++s) {
        int t = dir ? 127 - s : s;
        const unsigned long long* hin64 = reinterpret_cast<const unsigned long long*>(
            hstate + (long)(s & 1) * 65536 + (long)ed * 8192);
        __syncthreads();               // releases poll result to all waves
        // stage h(s-1): coherent 8B loads -> swizzled LDS
        #pragma unroll
        for (int i = 0; i < 4; ++i) {
            int idx = tid + 512 * i;               // 0..2047 (8B units)
            unsigned long long v = __hip_atomic_load(
                hin64 + idx, __ATOMIC_RELAXED, __HIP_MEMORY_SCOPE_AGENT);
            int r = idx >> 8, sb = (idx & 255) * 8;
            *reinterpret_cast<unsigned long long*>(
                (char*)hA + r * 2048 + (sb ^ ((r & 7) << 4))) = v;
        }
        // prefetch pre for gate threads
        float pz[8];
        if (tid < 64) {
            const unsigned short* prow =
                pre + (((long)e * 1024) + gb * 128 + t) * 8192 + dir * 4096 + cb * 16 + gp * 2;
            #pragma unroll
            for (int gg = 0; gg < 4; ++gg) {
                unsigned int u = *reinterpret_cast<const unsigned int*>(prow + gg * 1024);
                pz[gg * 2]     = bf2f((unsigned short)(u & 0xffff));
                pz[gg * 2 + 1] = bf2f((unsigned short)(u >> 16));
            }
        }
        __syncthreads();
        // MFMA: acc = h @ Wh[:, mycols]
        float4v acc = (float4v){0.f, 0.f, 0.f, 0.f};
        int abase = l15 * 2048, aswz = (l15 & 7) << 4;
        #pragma unroll
        for (int ks = 0; ks < 16; ++ks) {
            short8v a = *reinterpret_cast<const short8v*>(
                (char*)hA + abase + (((kh * 512 + ks * 32) * 2 + l4 * 16) ^ aswz));
            acc = __builtin_amdgcn_mfma_f32_16x16x32_bf16(a, wf[ks], acc, 0, 0, 0);
        }
        if (l4 < 2) {
            #pragma unroll
            for (int r = 0; r < 4; ++r)
                zred[g][kh][l4 * 4 + r][l15] = acc[r];
        }
        __syncthreads();
        if (tid < 64) {                // wave 0: gates + store + signal + poll
            int col0 = gp * 2;
            float h2[2];
            #pragma unroll
            for (int cc = 0; cc < 2; ++cc) {
                int col = col0 + cc;
                float zi = zred[0][0][gb][col] + zred[0][1][gb][col] + pz[0 + cc];
                float zf = zred[1][0][gb][col] + zred[1][1][gb][col] + pz[2 + cc];
                float zg = zred[2][0][gb][col] + zred[2][1][gb][col] + pz[4 + cc];
                float zo = zred[3][0][gb][col] + zred[3][1][gb][col] + pz[6 + cc];
                float ig = 1.f / (1.f + __expf(-zi));
                float fg = 1.f / (1.f + __expf(-zf));
                float gv = ftanh(zg);
                float og = 1.f / (1.f + __expf(-zo));
                float cv = cc ? c1 : c0;
                cv = fg * cv + ig * gv;
                if (cc) c1 = cv; else c0 = cv;
                h2[cc] = og * ftanh(cv);
            }
            unsigned int hv = (unsigned int)f2bf(h2[0]) | ((unsigned int)f2bf(h2[1]) << 16);
            int hcol = cb * 16 + col0;
            unsigned int* hout32 = reinterpret_cast<unsigned int*>(
                hstate + (long)((s & 1) ^ 1) * 65536 + (long)ed * 8192);
            __hip_atomic_store(hout32 + (gb * 1024 + hcol) / 2, hv,
                               __ATOMIC_RELAXED, __HIP_MEMORY_SCOPE_AGENT);
            *reinterpret_cast<unsigned int*>(
                memb + (((long)e * 8 + gb) * 128 + t) * 2048 + dir * 1024 + hcol) = hv;
            if (s < 127) {
                // wave-local drain: wave 0's h-stores acked at coherence point
                asm volatile("s_waitcnt vmcnt(0)" ::: "memory");
                if (tid == 0)
                    __hip_atomic_store(arr + cb, (unsigned)(s + 1),
                                       __ATOMIC_RELAXED, __HIP_MEMORY_SCOPE_AGENT);
                unsigned want = (unsigned)(s + 1);
                while (__hip_atomic_load(arr + tid, __ATOMIC_RELAXED,
                                         __HIP_MEMORY_SCOPE_AGENT) < want)
                    __builtin_amdgcn_s_sleep(1);
            }
        }
        // waves 1..7 skip to top-of-loop __syncthreads (released by wave 0)
    }
}

// ---------------- routed combine (fp32) ------------------------------------
__global__ __launch_bounds__(256) void combine_kernel(
    const float* __restrict__ outs, const float* __restrict__ router,
    float* __restrict__ out)
{
    int idx = blockIdx.x * 256 + threadIdx.x;
    int token = idx >> 7, q = (idx & 127) * 4;
    float4 r = *reinterpret_cast<const float4*>(&router[token * 4]);
    const float* bp = outs + (long)token * 512 + q;
    float4 v0 = *reinterpret_cast<const float4*>(bp);
    float4 v1 = *reinterpret_cast<const float4*>(bp + 524288);
    float4 v2 = *reinterpret_cast<const float4*>(bp + 1048576);
    float4 v3 = *reinterpret_cast<const float4*>(bp + 1572864);
    float4 a;
    a.x = r.x * v0.x + r.y * v1.x + r.z * v2.x + r.w * v3.x;
    a.y = r.x * v0.y + r.y * v1.y + r.z * v2.y + r.w * v3.y;
    a.z = r.x * v0.z + r.y * v1.z + r.z * v2.z + r.w * v3.z;
    a.w = r.x * v0.w + r.y * v1.w + r.z * v2.w + r.w * v3.w;
    *reinterpret_cast<float4*>(&out[(long)token * 512 + q]) = a;
}

extern "C" void kernel_launch(void* const* d_in, const int* in_sizes, int n_in,
                              void* d_out, int out_size, void* d_ws, size_t ws_size,
                              hipStream_t stream)
{
    (void)in_sizes; (void)n_in; (void)out_size; (void)ws_size;
    const float* x        = (const float*)d_in[0];
    const float* router_w = (const float*)d_in[1];
    const float* router_b = (const float*)d_in[2];
    const float* enc_w1   = (const float*)d_in[3];
    const float* enc_b1   = (const float*)d_in[4];
    const float* enc_w2   = (const float*)d_in[5];
    const float* enc_b2   = (const float*)d_in[6];
    const float* enc_g    = (const float*)d_in[7];
    const float* enc_beta = (const float*)d_in[8];
    const float* aiw      = (const float*)d_in[9];
    const float* aib      = (const float*)d_in[10];
    const float* aow      = (const float*)d_in[11];
    const float* aob      = (const float*)d_in[12];
    const float* wif      = (const float*)d_in[13];
    const float* whf      = (const float*)d_in[14];
    const float* bfv      = (const float*)d_in[15];
    const float* wib      = (const float*)d_in[16];
    const float* whb      = (const float*)d_in[17];
    const float* bbv      = (const float*)d_in[18];
    const float* sw1      = (const float*)d_in[19];
    const float* sb1      = (const float*)d_in[20];
    const float* sw2      = (const float*)d_in[21];
    const float* sb2      = (const float*)d_in[22];
    const float* tw1      = (const float*)d_in[23];
    const float* tb1      = (const float*)d_in[24];
    const float* tw2      = (const float*)d_in[25];
    const float* tb2      = (const float*)d_in[26];
    const float* dw1      = (const float*)d_in[27];
    const float* db1      = (const float*)d_in[28];
    const float* dw2      = (const float*)d_in[29];
    const float* db2      = (const float*)d_in[30];
    const float* dg       = (const float*)d_in[31];
    const float* dbeta    = (const float*)d_in[32];
    float* out = (float*)d_out;

    const long m = 1024L * 1024L;
    unsigned short* U = (unsigned short*)d_ws;
    unsigned short* ew1T = U;               // 2m
    unsigned short* ew2T = U + 2 * m;       // 4m
    unsigned short* aiwT = U + 6 * m;       // 12m
    unsigned short* aowT = U + 18 * m;      // 4m
    unsigned short* wiT  = U + 22 * m;      // 32m: [e][fwd4096|bwd4096][1024]
    unsigned short* whtf = U + 54 * m;      // 16m
    unsigned short* whtb = U + 70 * m;      // 16m
    unsigned short* gw1T = U + 86 * m;      // 16m: per-e 4m slab (sw1|tw1 cols)
    unsigned short* sw2T = U + 102 * m;     // 4m
    unsigned short* tw2T = U + 106 * m;     // 4m
    unsigned short* dw1T = U + 110 * m;     // 4m
    unsigned short* dw2T = U + 114 * m;     // 2m
    unsigned short* xb   = U + 116 * m;     // 0.5m
    unsigned short* hbuf = xb + 524288;     // 4m
    unsigned short* t1   = hbuf + 4 * m;    // 4m
    unsigned short* t2   = t1 + 4 * m;      // 4m
    unsigned short* pre  = t2 + 4 * m;      // 32m (early: qkv; late: gate1 out)
    unsigned short* memb = pre + 32 * m;    // 8m
    unsigned short* hstate = memb + 8 * m;  // 262144 ushorts (2 buffers)
    float* F      = (float*)(U + 170 * m);
    float* outs   = F;                      // 2m floats
    float* router = outs + 2 * m;           // 4096
    unsigned int* syncv = (unsigned int*)(router + 4096);  // 1024 uints

    hipMemsetAsync(hstate, 0, 65536 * sizeof(unsigned short), stream);
    hipMemsetAsync(syncv, 0, 1024 * sizeof(unsigned int), stream);

    // one-time conversions: x + all weights (one batched dispatch)
    cvt_bf16_kernel<<<512, 256, 0, stream>>>(x, xb, 131072);
    {
        TransJobs J;
        const float* srcs[14] = {enc_w1, enc_w2, aiw, aow, wif, wib, whf, whb,
                                 sw1, tw1, sw2, tw2, dw1, dw2};
        unsigned short* dsts[14] = {ew1T, ew2T, aiwT, aowT, wiT, wiT + 4096 * 1024L,
                                    whtf, whtb, gw1T, gw1T + 2 * m, sw2T, tw2T, dw1T, dw2T};
        int Ks[14] = {512, 1024, 1024, 1024, 1024, 1024, 1024, 1024,
                      2048, 2048, 1024, 1024, 1024, 1024};
        int Ns[14] = {1024, 1024, 3072, 1024, 4096, 4096, 4096, 4096,
                      1024, 1024, 1024, 1024, 1024, 512};
        long sWes[14] = {512 * 1024L, m, 3 * m, m, 4 * m, 4 * m, 4 * m, 4 * m,
                         2 * m, 2 * m, m, m, m, 512 * 1024L};
        long sTes[14] = {512 * 1024L, m, 3 * m, m, 8 * m, 8 * m, 4 * m, 4 * m,
                         4 * m, 4 * m, m, m, m, 512 * 1024L};
        int pfx = 0;
        J.prefix[0] = 0;
        for (int i = 0; i < 14; ++i) {
            J.src[i] = srcs[i]; J.dst[i] = dsts[i];
            J.K[i] = Ks[i]; J.N[i] = Ns[i];
            J.sWe[i] = sWes[i]; J.sTe[i] = sTes[i];
            pfx += (Ns[i] >> 5) * (Ks[i] >> 5) * 4;
            J.prefix[i + 1] = pfx;
        }
        transpose_all<<<pfx, 256, 0, stream>>>(J);
    }

    router_kernel<<<1024, 64, 0, stream>>>(x, router_w, router_b, router);

    // encoder
    gemm_bf16<1><<<dim3(8, 8, 4), 512, 0, stream>>>(xb, ew1T, enc_b1, enc_b1, nullptr, t1,
        1024, 512, 512, 1024, 0L, 512 * 1024L, 1024L, 0L, m, 1);
    gemm_bf16<1><<<dim3(8, 8, 4), 512, 0, stream>>>(t1, ew2T, enc_b2, enc_b2, nullptr, hbuf,
        1024, 1024, 1024, 1024, m, m, 1024L, 0L, m, 0);
    ln_bf16<1024><<<4096, 256, 0, stream>>>(hbuf, enc_g, enc_beta);
    // attention (qkv in pre region)
    gemm_bf16<1><<<dim3(24, 8, 4), 512, 0, stream>>>(hbuf, aiwT, aib, aib, nullptr, pre,
        3072, 1024, 1024, 3072, m, 3 * m, 3072L, 0L, 3 * m, 0);
    attn_bf16<<<512, 128, 0, stream>>>(pre, t1);
    gemm_bf16<1><<<dim3(8, 8, 4), 512, 0, stream>>>(t1, aowT, aob, aob, nullptr, hbuf,
        1024, 1024, 1024, 1024, m, m, 1024L, 0L, m, 0);
    // LSTM input projections, merged fwd|bwd: pre[e][tok][8192]
    gemm_bf16<1><<<dim3(64, 8, 4), 512, 0, stream>>>(hbuf, wiT, bfv, bbv, nullptr, pre,
        8192, 1024, 1024, 4096, m, 8 * m, 4096L, 0L, 8 * m, 0);
    // recurrence: one persistent kernel
    lstm_persistent<<<512, 512, 0, stream>>>(pre, whtf, whtb, hstate, memb, syncv);
    // gate branches: merged first layer (N=2048: sig|tan), out -> pre region
    unsigned short* g1o = pre;               // [E][1024][2048] bf16
    gemm_bf16<1><<<dim3(16, 8, 4), 512, 0, stream>>>(memb, gw1T, sb1, tb1, nullptr, g1o,
        2048, 2048, 2048, 1024, 2 * m, 4 * m, 1024L, 0L, 2 * m, 1);
    gemm_bf16<1><<<dim3(8, 8, 4), 512, 0, stream>>>(g1o, sw2T, sb2, sb2, nullptr, t2,
        1024, 1024, 2048, 1024, 2 * m, m, 1024L, 0L, m, 2);
    gemm_bf16<1><<<dim3(8, 8, 4), 512, 0, stream>>>(g1o + 1024, tw2T, tb2, tb2, t2, hbuf,
        1024, 1024, 2048, 1024, 2 * m, m, 1024L, m, m, 3);
    // decoder
    gemm_bf16<1><<<dim3(8, 8, 4), 512, 0, stream>>>(hbuf, dw1T, db1, db1, nullptr, t1,
        1024, 1024, 1024, 1024, m, m, 1024L, 0L, m, 1);
    gemm_bf16<0><<<dim3(4, 8, 4), 512, 0, stream>>>(t1, dw2T, db2, db2, nullptr, outs,
        512, 1024, 1024, 512, m, 512 * 1024L, 512L, 0L, 512 * 1024L, 0);
    ln_kernel<512><<<4096, 256, 0, stream>>>(outs, dg, dbeta);
    combine_kernel<<<512, 256, 0, stream>>>(outs, router, out);
}

// Round 10
// 1202.986 us; speedup vs baseline: 1.5656x; 1.1496x over previous
//
#include <hip/hip_runtime.h>

// B=8, S=128, IN=512, D=1024, E=4, NH=16, DH=64; tokens N=1024
// bf16 weights (transposed [N][K]) + MFMA 16x16x32; fp32 accumulate.
// LSTM: round-5 persistent kernel EXACTLY (known 628us): Wh in regs,
// relaxed-atomic h exchange, single-hop all-to-all tag barrier.
// GEMM: round-9 512-thread / 8-wave blocks (validated -107us).

typedef __attribute__((ext_vector_type(8))) short short8v;
typedef __attribute__((ext_vector_type(4))) float float4v;

__device__ __forceinline__ float bf2f(unsigned short u) {
    unsigned int x = ((unsigned int)u) << 16;
    return __builtin_bit_cast(float, x);
}
__device__ __forceinline__ unsigned short f2bf(float f) {
    unsigned int u = __builtin_bit_cast(unsigned int, f);
    u += 0x7fffu + ((u >> 16) & 1u);
    return (unsigned short)(u >> 16);
}
__device__ __forceinline__ void gload_lds16(const unsigned short* g, unsigned short* lds) {
    __builtin_amdgcn_global_load_lds(
        (const __attribute__((address_space(1))) unsigned int*)g,
        (__attribute__((address_space(3))) unsigned int*)lds, 16, 0, 0);
}
// inf-safe fast tanh via __expf (GEMM epilogue only; LSTM uses tanhf = r5 exact)
__device__ __forceinline__ float ftanh(float x) {
    float e = __expf(2.f * x);
    return 1.f - 2.f / (e + 1.f);
}

// ---------------- fp32 -> bf16 elementwise convert -------------------------
__global__ __launch_bounds__(256) void cvt_bf16_kernel(
    const float* __restrict__ in, unsigned short* __restrict__ out, int n4)
{
    int i = blockIdx.x * 256 + threadIdx.x;
    if (i >= n4) return;
    float4 v = *reinterpret_cast<const float4*>(&in[i * 4]);
    ushort4 o;
    o.x = f2bf(v.x); o.y = f2bf(v.y); o.z = f2bf(v.z); o.w = f2bf(v.w);
    *reinterpret_cast<ushort4*>(&out[i * 4]) = o;
}

// ---------------- batched W[K][N] fp32 -> Wt[N][K] bf16 (all weights) ------
struct TransJobs {
    const float* src[14];
    unsigned short* dst[14];
    int K[14], N[14];
    int prefix[15];
    long sWe[14], sTe[14];
};

__global__ __launch_bounds__(256) void transpose_all(TransJobs J)
{
    __shared__ float tile[32][33];
    int bid = blockIdx.x;
    int j = 0;
    #pragma unroll
    for (int i = 0; i < 14; ++i) if (bid >= J.prefix[i + 1]) j = i + 1;
    int lb = bid - J.prefix[j];
    int K = J.K[j], N = J.N[j];
    int tn = N >> 5, tk = K >> 5;
    int e = lb / (tn * tk), rem = lb % (tn * tk);
    int ky = rem / tn, nx = rem % tn;
    const float* W = J.src[j] + (long)e * J.sWe[j];
    unsigned short* Wt = J.dst[j] + (long)e * J.sTe[j];
    int k0 = ky * 32, n0 = nx * 32;
    int tx = threadIdx.x & 31, ty = threadIdx.x >> 5;
    #pragma unroll
    for (int i = 0; i < 32; i += 8)
        tile[ty + i][tx] = W[(long)(k0 + ty + i) * N + n0 + tx];
    __syncthreads();
    #pragma unroll
    for (int i = 0; i < 32; i += 8)
        Wt[(long)(n0 + ty + i) * K + k0 + tx] = f2bf(tile[tx][ty + i]);
}

// ---------------- router (fp32) --------------------------------------------
__global__ __launch_bounds__(64) void router_kernel(
    const float* __restrict__ x, const float* __restrict__ rw,
    const float* __restrict__ rb, float* __restrict__ router)
{
    int token = blockIdx.x;
    int lane = threadIdx.x;
    float a0 = 0.f, a1 = 0.f, a2 = 0.f, a3 = 0.f;
    const float* xp = x + (long)token * 512;
    for (int i = lane; i < 512; i += 64) {
        float xv = xp[i];
        const float* w = rw + (long)i * 4;
        a0 += xv * w[0]; a1 += xv * w[1]; a2 += xv * w[2]; a3 += xv * w[3];
    }
    #pragma unroll
    for (int off = 32; off; off >>= 1) {
        a0 += __shfl_down(a0, off); a1 += __shfl_down(a1, off);
        a2 += __shfl_down(a2, off); a3 += __shfl_down(a3, off);
    }
    if (lane == 0) {
        a0 += rb[0]; a1 += rb[1]; a2 += rb[2]; a3 += rb[3];
        float m = fmaxf(fmaxf(a0, a1), fmaxf(a2, a3));
        float e0 = __expf(a0 - m), e1 = __expf(a1 - m);
        float e2 = __expf(a2 - m), e3 = __expf(a3 - m);
        float inv = 1.f / (e0 + e1 + e2 + e3);
        *reinterpret_cast<float4*>(&router[token * 4]) =
            make_float4(e0 * inv, e1 * inv, e2 * inv, e3 * inv);
    }
}

// ---------------- MFMA bf16 GEMM: C = act(A@W + bias) [*mul] ---------------
// 512 threads / 8 waves: wave w -> rows [wr*64,+64), cols [wc*32,+32).
// Double-buffered LDS, counted vmcnt(4), loads in flight across barriers.
template <int OUTBF>
__global__ __launch_bounds__(512) void gemm_bf16(
    const unsigned short* __restrict__ A, const unsigned short* __restrict__ Wt,
    const float* __restrict__ bias, const float* __restrict__ bias2,
    const unsigned short* __restrict__ mul,
    void* __restrict__ Cv, int N, int K, int lda, int nsplit,
    long sAe, long sWe, long sBe, long sMe, long sCe, int act)
{
    __shared__ unsigned short As[2][128 * 64];
    __shared__ unsigned short Bs[2][128 * 64];
    int e = blockIdx.z;
    A += (long)e * sAe; Wt += (long)e * sWe;
    bias += (long)e * sBe; bias2 += (long)e * sBe;
    if (mul) mul += (long)e * sMe;
    int tid = threadIdx.x;
    int row0 = blockIdx.y * 128, col0 = blockIdx.x * 128;
    int wid = tid >> 6, lane = tid & 63;
    int wr = wid >> 2, wc = wid & 3;
    int l15 = lane & 15, l4 = lane >> 4;
    int r8 = lane >> 3, sg = lane & 7;
    float4v acc[4][2];
    #pragma unroll
    for (int i = 0; i < 4; ++i)
        #pragma unroll
        for (int j = 0; j < 2; ++j) acc[i][j] = (float4v){0.f, 0.f, 0.f, 0.f};

    auto STAGE = [&](int buf, int k0) {
        #pragma unroll
        for (int c = 0; c < 2; ++c) {
            int chunk = wid * 2 + c;                  // 0..15
            int rowA = chunk * 8 + r8;
            int segA = (sg ^ (rowA & 7)) * 8;
            gload_lds16(A + (long)(row0 + rowA) * lda + k0 + segA,
                        (unsigned short*)((char*)As[buf] + chunk * 1024));
            gload_lds16(Wt + (long)(col0 + rowA) * K + k0 + segA,
                        (unsigned short*)((char*)Bs[buf] + chunk * 1024));
        }
    };
    int nt = K >> 6;
    STAGE(0, 0);
    for (int t = 0; t < nt; ++t) {
        int cur = t & 1;
        if (t + 1 < nt) {
            STAGE(cur ^ 1, (t + 1) << 6);
            asm volatile("s_waitcnt vmcnt(4)" ::: "memory");
        } else {
            asm volatile("s_waitcnt vmcnt(0)" ::: "memory");
        }
        __builtin_amdgcn_s_barrier();
        __builtin_amdgcn_sched_barrier(0);
        #pragma unroll
        for (int kk = 0; kk < 2; ++kk) {
            short8v af[4], bq[2];
            int bytec = kk * 64 + l4 * 16;
            #pragma unroll
            for (int m = 0; m < 4; ++m) {
                int r = wr * 64 + m * 16 + l15;
                af[m] = *reinterpret_cast<const short8v*>(
                    (char*)As[cur] + r * 128 + (bytec ^ ((r & 7) << 4)));
            }
            #pragma unroll
            for (int n = 0; n < 2; ++n) {
                int r = wc * 32 + n * 16 + l15;
                bq[n] = *reinterpret_cast<const short8v*>(
                    (char*)Bs[cur] + r * 128 + (bytec ^ ((r & 7) << 4)));
            }
            #pragma unroll
            for (int m = 0; m < 4; ++m)
                #pragma unroll
                for (int n = 0; n < 2; ++n)
                    acc[m][n] = __builtin_amdgcn_mfma_f32_16x16x32_bf16(
                        af[m], bq[n], acc[m][n], 0, 0, 0);
        }
        __builtin_amdgcn_sched_barrier(0);
        __builtin_amdgcn_s_barrier();
    }
    float* Cf = (float*)Cv + (long)e * sCe;
    unsigned short* Cb = (unsigned short*)Cv + (long)e * sCe;
    #pragma unroll
    for (int n = 0; n < 2; ++n) {
        int col = col0 + wc * 32 + n * 16 + l15;
        float bia = (col < nsplit) ? bias[col] : bias2[col - nsplit];
        #pragma unroll
        for (int m = 0; m < 4; ++m) {
            #pragma unroll
            for (int r = 0; r < 4; ++r) {
                long row = row0 + wr * 64 + m * 16 + l4 * 4 + r;
                float v = acc[m][n][r] + bia;
                if (act == 1) v = fmaxf(v, 0.f);
                else if (act == 2) v = 1.f / (1.f + __expf(-v));
                else if (act == 3) v = ftanh(v);
                if (mul) v *= bf2f(mul[row * N + col]);
                if (OUTBF) Cb[row * N + col] = f2bf(v);
                else       Cf[row * N + col] = v;
            }
        }
    }
}

// ---------------- LayerNorm bf16 in/out (DIM=1024) -------------------------
template <int DIM>
__global__ __launch_bounds__(256) void ln_bf16(
    unsigned short* __restrict__ buf, const float* __restrict__ g,
    const float* __restrict__ beta)
{
    constexpr int PT = DIM / 256;
    __shared__ float sbuf[4];
    int row = blockIdx.x, e = row >> 10;
    unsigned short* p = buf + (long)row * DIM;
    const float* gp = g + (long)e * DIM;
    const float* bp = beta + (long)e * DIM;
    int tid = threadIdx.x;
    float v[PT];
    ushort4 u = *reinterpret_cast<const ushort4*>(p + tid * PT);
    v[0] = bf2f(u.x); v[1] = bf2f(u.y); v[2] = bf2f(u.z); v[3] = bf2f(u.w);
    float s = v[0] + v[1] + v[2] + v[3];
    #pragma unroll
    for (int off = 32; off; off >>= 1) s += __shfl_down(s, off);
    if ((tid & 63) == 0) sbuf[tid >> 6] = s;
    __syncthreads();
    float mean = (sbuf[0] + sbuf[1] + sbuf[2] + sbuf[3]) / (float)DIM;
    __syncthreads();
    float vs = 0.f;
    #pragma unroll
    for (int i = 0; i < PT; ++i) { float d = v[i] - mean; vs += d * d; }
    #pragma unroll
    for (int off = 32; off; off >>= 1) vs += __shfl_down(vs, off);
    if ((tid & 63) == 0) sbuf[tid >> 6] = vs;
    __syncthreads();
    float var = (sbuf[0] + sbuf[1] + sbuf[2] + sbuf[3]) / (float)DIM;
    float rstd = rsqrtf(var + 1e-5f);
    ushort4 o;
    o.x = f2bf((v[0] - mean) * rstd * gp[tid * PT + 0] + bp[tid * PT + 0]);
    o.y = f2bf((v[1] - mean) * rstd * gp[tid * PT + 1] + bp[tid * PT + 1]);
    o.z = f2bf((v[2] - mean) * rstd * gp[tid * PT + 2] + bp[tid * PT + 2]);
    o.w = f2bf((v[3] - mean) * rstd * gp[tid * PT + 3] + bp[tid * PT + 3]);
    *reinterpret_cast<ushort4*>(p + tid * PT) = o;
}

// ---------------- LayerNorm fp32 in-place (DIM=512 final) ------------------
template <int DIM>
__global__ __launch_bounds__(256) void ln_kernel(
    float* __restrict__ buf, const float* __restrict__ g,
    const float* __restrict__ beta)
{
    constexpr int PT = DIM / 256;
    __shared__ float sbuf[4];
    int row = blockIdx.x, e = row >> 10;
    float* p = buf + (long)row * DIM;
    const float* gp = g + (long)e * DIM;
    const float* bp = beta + (long)e * DIM;
    int tid = threadIdx.x;
    float v[PT];
    float s = 0.f;
    #pragma unroll
    for (int i = 0; i < PT; ++i) { v[i] = p[tid + i * 256]; s += v[i]; }
    #pragma unroll
    for (int off = 32; off; off >>= 1) s += __shfl_down(s, off);
    if ((tid & 63) == 0) sbuf[tid >> 6] = s;
    __syncthreads();
    float mean = (sbuf[0] + sbuf[1] + sbuf[2] + sbuf[3]) / (float)DIM;
    __syncthreads();
    float vs = 0.f;
    #pragma unroll
    for (int i = 0; i < PT; ++i) { float d = v[i] - mean; vs += d * d; }
    #pragma unroll
    for (int off = 32; off; off >>= 1) vs += __shfl_down(vs, off);
    if ((tid & 63) == 0) sbuf[tid >> 6] = vs;
    __syncthreads();
    float var = (sbuf[0] + sbuf[1] + sbuf[2] + sbuf[3]) / (float)DIM;
    float rstd = rsqrtf(var + 1e-5f);
    #pragma unroll
    for (int i = 0; i < PT; ++i)
        p[tid + i * 256] = (v[i] - mean) * rstd * gp[tid + i * 256] + bp[tid + i * 256];
}

// ---------------- fused attention, bf16 in/out -----------------------------
__global__ __launch_bounds__(128) void attn_bf16(
    const unsigned short* __restrict__ qkv, unsigned short* __restrict__ o)
{
    __shared__ __align__(16) float Ks[128][64];
    __shared__ __align__(16) float Vs[128][64];
    int id = blockIdx.x;
    int hd = id & 15, b = (id >> 4) & 7, e = id >> 7;
    int tid = threadIdx.x;
    const long base = ((long)e * 1024 + b * 128) * 3072 + hd * 64;
    #pragma unroll
    for (int i = 0; i < 8; ++i) {
        int idx = i * 128 + tid;
        int row = idx >> 3, f8 = (idx & 7) * 8;
        short8v kv = *reinterpret_cast<const short8v*>(&qkv[base + (long)row * 3072 + 1024 + f8]);
        short8v vv = *reinterpret_cast<const short8v*>(&qkv[base + (long)row * 3072 + 2048 + f8]);
        #pragma unroll
        for (int j = 0; j < 8; ++j) {
            Ks[row][f8 + j] = bf2f((unsigned short)kv[j]);
            Vs[row][f8 + j] = bf2f((unsigned short)vv[j]);
        }
    }
    __syncthreads();
    float q[64];
    #pragma unroll
    for (int f = 0; f < 8; ++f) {
        short8v qv = *reinterpret_cast<const short8v*>(&qkv[base + (long)tid * 3072 + f * 8]);
        #pragma unroll
        for (int j = 0; j < 8; ++j) q[f * 8 + j] = bf2f((unsigned short)qv[j]);
    }
    float m = -__builtin_huge_valf(), l = 0.f;
    float oa[64];
    #pragma unroll
    for (int d = 0; d < 64; ++d) oa[d] = 0.f;
    for (int j = 0; j < 128; ++j) {
        float s = 0.f;
        #pragma unroll
        for (int d = 0; d < 64; ++d) s = fmaf(q[d], Ks[j][d], s);
        s *= 0.125f;
        float mn = fmaxf(m, s);
        float corr = __expf(m - mn);
        float pj = __expf(s - mn);
        l = l * corr + pj;
        #pragma unroll
        for (int d = 0; d < 64; ++d) oa[d] = oa[d] * corr + pj * Vs[j][d];
        m = mn;
    }
    float inv = 1.f / l;
    unsigned short* op = o + ((long)e * 1024 + b * 128 + tid) * 1024 + hd * 64;
    #pragma unroll
    for (int f = 0; f < 8; ++f) {
        short8v ov;
        #pragma unroll
        for (int j = 0; j < 8; ++j) ov[j] = (short)f2bf(oa[f * 8 + j] * inv);
        *reinterpret_cast<short8v*>(&op[f * 8]) = ov;
    }
}

// ---------------- persistent LSTM (round-5 exact) ---------------------------
// grid 512 x 512thr; chain ed = bid&7, cb = bid>>3 (16 h-cols each).
// h exchange: relaxed agent-scope atomics. Barrier: single-hop all-to-all
// (signal own slot, wave0 sweeps 64 monotonic slots).
__global__ __launch_bounds__(512, 4) void lstm_persistent(
    const unsigned short* __restrict__ pre, const unsigned short* __restrict__ whtf,
    const unsigned short* __restrict__ whtb, unsigned short* __restrict__ hstate,
    unsigned short* __restrict__ memb, unsigned int* __restrict__ sync)
{
    __shared__ unsigned short hA[16 * 1024];       // 32KB swizzled A-operand
    __shared__ float zred[4][2][8][16];            // gate, khalf, batch, col
    int bid = blockIdx.x;
    int ed = bid & 7, cb = bid >> 3;
    int e = ed >> 1, dir = ed & 1;
    const unsigned short* Wt = (dir ? whtb : whtf) + (long)e * 4096 * 1024;
    unsigned int* arr = sync + ed * 64;            // [8][64] arrival slots
    int tid = threadIdx.x;
    int w = tid >> 6, lane = tid & 63, l15 = lane & 15, l4 = lane >> 4;
    int g = w >> 1, kh = w & 1;
    // one-time: weight fragments into registers
    short8v wf[16];
    const unsigned short* wp =
        Wt + ((long)(g * 1024 + cb * 16 + l15)) * 1024 + kh * 512 + l4 * 8;
    #pragma unroll
    for (int ks = 0; ks < 16; ++ks)
        wf[ks] = *reinterpret_cast<const short8v*>(wp + ks * 32);
    // one-time: zero pad rows 8..15 of hA
    short8v z8 = {0, 0, 0, 0, 0, 0, 0, 0};
    for (int i = tid; i < 8 * 128; i += 512) {
        int r = 8 + (i >> 7), sb = (i & 127) * 16;
        *reinterpret_cast<short8v*>((char*)hA + r * 2048 + (sb ^ ((r & 7) << 4))) = z8;
    }
    float c0 = 0.f, c1 = 0.f;                      // c-state (gate threads)
    int gp = tid & 7, gb = tid >> 3;               // gate mapping (tid<64)
    for (int s = 0; s < 128; ++s) {
        int t = dir ? 127 - s : s;
        const unsigned long long* hin64 = reinterpret_cast<const unsigned long long*>(
            hstate + (long)(s & 1) * 65536 + (long)ed * 8192);
        __syncthreads();
        // stage h(s-1): coherent 8B loads -> swizzled LDS
        #pragma unroll
        for (int i = 0; i < 4; ++i) {
            int idx = tid + 512 * i;               // 0..2047 (8B units)
            unsigned long long v = __hip_atomic_load(
                hin64 + idx, __ATOMIC_RELAXED, __HIP_MEMORY_SCOPE_AGENT);
            int r = idx >> 8, sb = (idx & 255) * 8;
            *reinterpret_cast<unsigned long long*>(
                (char*)hA + r * 2048 + (sb ^ ((r & 7) << 4))) = v;
        }
        // prefetch pre for gate threads
        float pz[8];
        if (tid < 64) {
            const unsigned short* prow =
                pre + (((long)e * 1024) + gb * 128 + t) * 8192 + dir * 4096 + cb * 16 + gp * 2;
            #pragma unroll
            for (int gg = 0; gg < 4; ++gg) {
                unsigned int u = *reinterpret_cast<const unsigned int*>(prow + gg * 1024);
                pz[gg * 2]     = bf2f((unsigned short)(u & 0xffff));
                pz[gg * 2 + 1] = bf2f((unsigned short)(u >> 16));
            }
        }
        __syncthreads();
        // MFMA: acc = h @ Wh[:, mycols]
        float4v acc = (float4v){0.f, 0.f, 0.f, 0.f};
        int abase = l15 * 2048, aswz = (l15 & 7) << 4;
        #pragma unroll
        for (int ks = 0; ks < 16; ++ks) {
            short8v a = *reinterpret_cast<const short8v*>(
                (char*)hA + abase + (((kh * 512 + ks * 32) * 2 + l4 * 16) ^ aswz));
            acc = __builtin_amdgcn_mfma_f32_16x16x32_bf16(a, wf[ks], acc, 0, 0, 0);
        }
        if (l4 < 2) {
            #pragma unroll
            for (int r = 0; r < 4; ++r)
                zred[g][kh][l4 * 4 + r][l15] = acc[r];
        }
        __syncthreads();
        if (tid < 64) {
            int col0 = gp * 2;
            float h2[2];
            #pragma unroll
            for (int cc = 0; cc < 2; ++cc) {
                int col = col0 + cc;
                float zi = zred[0][0][gb][col] + zred[0][1][gb][col] + pz[0 + cc];
                float zf = zred[1][0][gb][col] + zred[1][1][gb][col] + pz[2 + cc];
                float zg = zred[2][0][gb][col] + zred[2][1][gb][col] + pz[4 + cc];
                float zo = zred[3][0][gb][col] + zred[3][1][gb][col] + pz[6 + cc];
                float ig = 1.f / (1.f + __expf(-zi));
                float fg = 1.f / (1.f + __expf(-zf));
                float gv = tanhf(zg);
                float og = 1.f / (1.f + __expf(-zo));
                float cv = cc ? c1 : c0;
                cv = fg * cv + ig * gv;
                if (cc) c1 = cv; else c0 = cv;
                h2[cc] = og * tanhf(cv);
            }
            unsigned int hv = (unsigned int)f2bf(h2[0]) | ((unsigned int)f2bf(h2[1]) << 16);
            int hcol = cb * 16 + col0;
            unsigned int* hout32 = reinterpret_cast<unsigned int*>(
                hstate + (long)((s & 1) ^ 1) * 65536 + (long)ed * 8192);
            __hip_atomic_store(hout32 + (gb * 1024 + hcol) / 2, hv,
                               __ATOMIC_RELAXED, __HIP_MEMORY_SCOPE_AGENT);
            *reinterpret_cast<unsigned int*>(
                memb + (((long)e * 8 + gb) * 128 + t) * 2048 + dir * 1024 + hcol) = hv;
        }
        if (s == 127) break;           // last step: no consumer, skip barrier
        __syncthreads();               // drains vmcnt: h stores at coherence pt
        // single-hop all-to-all: signal own slot, wave0 sweeps all 64
        if (tid == 0)
            __hip_atomic_store(arr + cb, (unsigned)(s + 1), __ATOMIC_RELAXED,
                               __HIP_MEMORY_SCOPE_AGENT);
        if (tid < 64) {
            while (__hip_atomic_load(arr + tid, __ATOMIC_RELAXED,
                                     __HIP_MEMORY_SCOPE_AGENT) < (unsigned)(s + 1))
                __builtin_amdgcn_s_sleep(1);
        }
        // top-of-loop __syncthreads() completes the barrier block-wide
    }
}

// ---------------- routed combine (fp32) ------------------------------------
__global__ __launch_bounds__(256) void combine_kernel(
    const float* __restrict__ outs, const float* __restrict__ router,
    float* __restrict__ out)
{
    int idx = blockIdx.x * 256 + threadIdx.x;
    int token = idx >> 7, q = (idx & 127) * 4;
    float4 r = *reinterpret_cast<const float4*>(&router[token * 4]);
    const float* bp = outs + (long)token * 512 + q;
    float4 v0 = *reinterpret_cast<const float4*>(bp);
    float4 v1 = *reinterpret_cast<const float4*>(bp + 524288);
    float4 v2 = *reinterpret_cast<const float4*>(bp + 1048576);
    float4 v3 = *reinterpret_cast<const float4*>(bp + 1572864);
    float4 a;
    a.x = r.x * v0.x + r.y * v1.x + r.z * v2.x + r.w * v3.x;
    a.y = r.x * v0.y + r.y * v1.y + r.z * v2.y + r.w * v3.y;
    a.z = r.x * v0.z + r.y * v1.z + r.z * v2.z + r.w * v3.z;
    a.w = r.x * v0.w + r.y * v1.w + r.z * v2.w + r.w * v3.w;
    *reinterpret_cast<float4*>(&out[(long)token * 512 + q]) = a;
}

extern "C" void kernel_launch(void* const* d_in, const int* in_sizes, int n_in,
                              void* d_out, int out_size, void* d_ws, size_t ws_size,
                              hipStream_t stream)
{
    (void)in_sizes; (void)n_in; (void)out_size; (void)ws_size;
    const float* x        = (const float*)d_in[0];
    const float* router_w = (const float*)d_in[1];
    const float* router_b = (const float*)d_in[2];
    const float* enc_w1   = (const float*)d_in[3];
    const float* enc_b1   = (const float*)d_in[4];
    const float* enc_w2   = (const float*)d_in[5];
    const float* enc_b2   = (const float*)d_in[6];
    const float* enc_g    = (const float*)d_in[7];
    const float* enc_beta = (const float*)d_in[8];
    const float* aiw      = (const float*)d_in[9];
    const float* aib      = (const float*)d_in[10];
    const float* aow      = (const float*)d_in[11];
    const float* aob      = (const float*)d_in[12];
    const float* wif      = (const float*)d_in[13];
    const float* whf      = (const float*)d_in[14];
    const float* bfv      = (const float*)d_in[15];
    const float* wib      = (const float*)d_in[16];
    const float* whb      = (const float*)d_in[17];
    const float* bbv      = (const float*)d_in[18];
    const float* sw1      = (const float*)d_in[19];
    const float* sb1      = (const float*)d_in[20];
    const float* sw2      = (const float*)d_in[21];
    const float* sb2      = (const float*)d_in[22];
    const float* tw1      = (const float*)d_in[23];
    const float* tb1      = (const float*)d_in[24];
    const float* tw2      = (const float*)d_in[25];
    const float* tb2      = (const float*)d_in[26];
    const float* dw1      = (const float*)d_in[27];
    const float* db1      = (const float*)d_in[28];
    const float* dw2      = (const float*)d_in[29];
    const float* db2      = (const float*)d_in[30];
    const float* dg       = (const float*)d_in[31];
    const float* dbeta    = (const float*)d_in[32];
    float* out = (float*)d_out;

    const long m = 1024L * 1024L;
    unsigned short* U = (unsigned short*)d_ws;
    unsigned short* ew1T = U;               // 2m
    unsigned short* ew2T = U + 2 * m;       // 4m
    unsigned short* aiwT = U + 6 * m;       // 12m
    unsigned short* aowT = U + 18 * m;      // 4m
    unsigned short* wiT  = U + 22 * m;      // 32m: [e][fwd4096|bwd4096][1024]
    unsigned short* whtf = U + 54 * m;      // 16m
    unsigned short* whtb = U + 70 * m;      // 16m
    unsigned short* gw1T = U + 86 * m;      // 16m: per-e 4m slab (sw1|tw1 cols)
    unsigned short* sw2T = U + 102 * m;     // 4m
    unsigned short* tw2T = U + 106 * m;     // 4m
    unsigned short* dw1T = U + 110 * m;     // 4m
    unsigned short* dw2T = U + 114 * m;     // 2m
    unsigned short* xb   = U + 116 * m;     // 0.5m
    unsigned short* hbuf = xb + 524288;     // 4m
    unsigned short* t1   = hbuf + 4 * m;    // 4m
    unsigned short* t2   = t1 + 4 * m;      // 4m
    unsigned short* pre  = t2 + 4 * m;      // 32m (early: qkv; late: gate1 out)
    unsigned short* memb = pre + 32 * m;    // 8m
    unsigned short* hstate = memb + 8 * m;  // 262144 ushorts (2 buffers)
    float* F      = (float*)(U + 170 * m);
    float* outs   = F;                      // 2m floats
    float* router = outs + 2 * m;           // 4096
    unsigned int* syncv = (unsigned int*)(router + 4096);  // 1024 uints

    hipMemsetAsync(hstate, 0, 65536 * sizeof(unsigned short), stream);
    hipMemsetAsync(syncv, 0, 1024 * sizeof(unsigned int), stream);

    // one-time conversions: x + all weights (one batched dispatch)
    cvt_bf16_kernel<<<512, 256, 0, stream>>>(x, xb, 131072);
    {
        TransJobs J;
        const float* srcs[14] = {enc_w1, enc_w2, aiw, aow, wif, wib, whf, whb,
                                 sw1, tw1, sw2, tw2, dw1, dw2};
        unsigned short* dsts[14] = {ew1T, ew2T, aiwT, aowT, wiT, wiT + 4096 * 1024L,
                                    whtf, whtb, gw1T, gw1T + 2 * m, sw2T, tw2T, dw1T, dw2T};
        int Ks[14] = {512, 1024, 1024, 1024, 1024, 1024, 1024, 1024,
                      2048, 2048, 1024, 1024, 1024, 1024};
        int Ns[14] = {1024, 1024, 3072, 1024, 4096, 4096, 4096, 4096,
                      1024, 1024, 1024, 1024, 1024, 512};
        long sWes[14] = {512 * 1024L, m, 3 * m, m, 4 * m, 4 * m, 4 * m, 4 * m,
                         2 * m, 2 * m, m, m, m, 512 * 1024L};
        long sTes[14] = {512 * 1024L, m, 3 * m, m, 8 * m, 8 * m, 4 * m, 4 * m,
                         4 * m, 4 * m, m, m, m, 512 * 1024L};
        int pfx = 0;
        J.prefix[0] = 0;
        for (int i = 0; i < 14; ++i) {
            J.src[i] = srcs[i]; J.dst[i] = dsts[i];
            J.K[i] = Ks[i]; J.N[i] = Ns[i];
            J.sWe[i] = sWes[i]; J.sTe[i] = sTes[i];
            pfx += (Ns[i] >> 5) * (Ks[i] >> 5) * 4;
            J.prefix[i + 1] = pfx;
        }
        transpose_all<<<pfx, 256, 0, stream>>>(J);
    }

    router_kernel<<<1024, 64, 0, stream>>>(x, router_w, router_b, router);

    // encoder
    gemm_bf16<1><<<dim3(8, 8, 4), 512, 0, stream>>>(xb, ew1T, enc_b1, enc_b1, nullptr, t1,
        1024, 512, 512, 1024, 0L, 512 * 1024L, 1024L, 0L, m, 1);
    gemm_bf16<1><<<dim3(8, 8, 4), 512, 0, stream>>>(t1, ew2T, enc_b2, enc_b2, nullptr, hbuf,
        1024, 1024, 1024, 1024, m, m, 1024L, 0L, m, 0);
    ln_bf16<1024><<<4096, 256, 0, stream>>>(hbuf, enc_g, enc_beta);
    // attention (qkv in pre region)
    gemm_bf16<1><<<dim3(24, 8, 4), 512, 0, stream>>>(hbuf, aiwT, aib, aib, nullptr, pre,
        3072, 1024, 1024, 3072, m, 3 * m, 3072L, 0L, 3 * m, 0);
    attn_bf16<<<512, 128, 0, stream>>>(pre, t1);
    gemm_bf16<1><<<dim3(8, 8, 4), 512, 0, stream>>>(t1, aowT, aob, aob, nullptr, hbuf,
        1024, 1024, 1024, 1024, m, m, 1024L, 0L, m, 0);
    // LSTM input projections, merged fwd|bwd: pre[e][tok][8192]
    gemm_bf16<1><<<dim3(64, 8, 4), 512, 0, stream>>>(hbuf, wiT, bfv, bbv, nullptr, pre,
        8192, 1024, 1024, 4096, m, 8 * m, 4096L, 0L, 8 * m, 0);
    // recurrence: one persistent kernel
    lstm_persistent<<<512, 512, 0, stream>>>(pre, whtf, whtb, hstate, memb, syncv);
    // gate branches: merged first layer (N=2048: sig|tan), out -> pre region
    unsigned short* g1o = pre;               // [E][1024][2048] bf16
    gemm_bf16<1><<<dim3(16, 8, 4), 512, 0, stream>>>(memb, gw1T, sb1, tb1, nullptr, g1o,
        2048, 2048, 2048, 1024, 2 * m, 4 * m, 1024L, 0L, 2 * m, 1);
    gemm_bf16<1><<<dim3(8, 8, 4), 512, 0, stream>>>(g1o, sw2T, sb2, sb2, nullptr, t2,
        1024, 1024, 2048, 1024, 2 * m, m, 1024L, 0L, m, 2);
    gemm_bf16<1><<<dim3(8, 8, 4), 512, 0, stream>>>(g1o + 1024, tw2T, tb2, tb2, t2, hbuf,
        1024, 1024, 2048, 1024, 2 * m, m, 1024L, m, m, 3);
    // decoder
    gemm_bf16<1><<<dim3(8, 8, 4), 512, 0, stream>>>(hbuf, dw1T, db1, db1, nullptr, t1,
        1024, 1024, 1024, 1024, m, m, 1024L, 0L, m, 1);
    gemm_bf16<0><<<dim3(4, 8, 4), 512, 0, stream>>>(t1, dw2T, db2, db2, nullptr, outs,
        512, 1024, 1024, 512, m, 512 * 1024L, 512L, 0L, 512 * 1024L, 0);
    ln_kernel<512><<<4096, 256, 0, stream>>>(outs, dg, dbeta);
    combine_kernel<<<512, 256, 0, stream>>>(outs, router, out);
}

// Round 11
// 1201.643 us; speedup vs baseline: 1.5674x; 1.0011x over previous
//
#include <hip/hip_runtime.h>

// B=8, S=128, IN=512, D=1024, E=4, NH=16, DH=64; tokens N=1024
// bf16 weights (transposed [N][K]) + MFMA 16x16x32; fp32 accumulate.
// LSTM: round-5 persistent kernel EXACTLY (known 628us).
// GEMM: 512-thr / 8-wave, double-buffered LDS, SINGLE barrier per K-step
// (T3 minimum 2-phase recipe). Transpose: vectorized 128B writes.

typedef __attribute__((ext_vector_type(8))) short short8v;
typedef __attribute__((ext_vector_type(4))) float float4v;

__device__ __forceinline__ float bf2f(unsigned short u) {
    unsigned int x = ((unsigned int)u) << 16;
    return __builtin_bit_cast(float, x);
}
__device__ __forceinline__ unsigned short f2bf(float f) {
    unsigned int u = __builtin_bit_cast(unsigned int, f);
    u += 0x7fffu + ((u >> 16) & 1u);
    return (unsigned short)(u >> 16);
}
__device__ __forceinline__ void gload_lds16(const unsigned short* g, unsigned short* lds) {
    __builtin_amdgcn_global_load_lds(
        (const __attribute__((address_space(1))) unsigned int*)g,
        (__attribute__((address_space(3))) unsigned int*)lds, 16, 0, 0);
}
// inf-safe fast tanh via __expf (GEMM epilogue only; LSTM uses tanhf = r5 exact)
__device__ __forceinline__ float ftanh(float x) {
    float e = __expf(2.f * x);
    return 1.f - 2.f / (e + 1.f);
}

// ---------------- fp32 -> bf16 elementwise convert -------------------------
__global__ __launch_bounds__(256) void cvt_bf16_kernel(
    const float* __restrict__ in, unsigned short* __restrict__ out, int n4)
{
    int i = blockIdx.x * 256 + threadIdx.x;
    if (i >= n4) return;
    float4 v = *reinterpret_cast<const float4*>(&in[i * 4]);
    ushort4 o;
    o.x = f2bf(v.x); o.y = f2bf(v.y); o.z = f2bf(v.z); o.w = f2bf(v.w);
    *reinterpret_cast<ushort4*>(&out[i * 4]) = o;
}

// ---------------- batched W[K][N] fp32 -> Wt[N][K] bf16 (all weights) ------
// 64k x 32n tiles; reads 128B-coalesced, writes packed uint (2k) 128B rows.
struct TransJobs {
    const float* src[14];
    unsigned short* dst[14];
    int K[14], N[14];
    int prefix[15];
    long sWe[14], sTe[14];
};

__global__ __launch_bounds__(256) void transpose_all(TransJobs J)
{
    __shared__ float tile[64][33];
    int bid = blockIdx.x;
    int j = 0;
    #pragma unroll
    for (int i = 0; i < 14; ++i) if (bid >= J.prefix[i + 1]) j = i + 1;
    int lb = bid - J.prefix[j];
    int K = J.K[j], N = J.N[j];
    int tn = N >> 5, tk = K >> 6;
    int e = lb / (tn * tk), rem = lb % (tn * tk);
    int ky = rem / tn, nx = rem % tn;
    const float* W = J.src[j] + (long)e * J.sWe[j];
    unsigned short* Wt = J.dst[j] + (long)e * J.sTe[j];
    int k0 = ky * 64, n0 = nx * 32;
    int tx = threadIdx.x & 31, ty = threadIdx.x >> 5;     // ty 0..7
    #pragma unroll
    for (int i = 0; i < 64; i += 8)
        tile[ty + i][tx] = W[(long)(k0 + ty + i) * N + n0 + tx];
    __syncthreads();
    // write: 8 n-rows per pass x 4 passes; each lane packs 2 consecutive k
    #pragma unroll
    for (int p = 0; p < 4; ++p) {
        int nn = ty + p * 8;
        unsigned lo = (unsigned)f2bf(tile[tx * 2][nn]);
        unsigned hi = (unsigned)f2bf(tile[tx * 2 + 1][nn]);
        *reinterpret_cast<unsigned*>(&Wt[(long)(n0 + nn) * K + k0 + tx * 2]) =
            lo | (hi << 16);
    }
}

// ---------------- router (fp32) --------------------------------------------
__global__ __launch_bounds__(64) void router_kernel(
    const float* __restrict__ x, const float* __restrict__ rw,
    const float* __restrict__ rb, float* __restrict__ router)
{
    int token = blockIdx.x;
    int lane = threadIdx.x;
    float a0 = 0.f, a1 = 0.f, a2 = 0.f, a3 = 0.f;
    const float* xp = x + (long)token * 512;
    for (int i = lane; i < 512; i += 64) {
        float xv = xp[i];
        const float* w = rw + (long)i * 4;
        a0 += xv * w[0]; a1 += xv * w[1]; a2 += xv * w[2]; a3 += xv * w[3];
    }
    #pragma unroll
    for (int off = 32; off; off >>= 1) {
        a0 += __shfl_down(a0, off); a1 += __shfl_down(a1, off);
        a2 += __shfl_down(a2, off); a3 += __shfl_down(a3, off);
    }
    if (lane == 0) {
        a0 += rb[0]; a1 += rb[1]; a2 += rb[2]; a3 += rb[3];
        float m = fmaxf(fmaxf(a0, a1), fmaxf(a2, a3));
        float e0 = __expf(a0 - m), e1 = __expf(a1 - m);
        float e2 = __expf(a2 - m), e3 = __expf(a3 - m);
        float inv = 1.f / (e0 + e1 + e2 + e3);
        *reinterpret_cast<float4*>(&router[token * 4]) =
            make_float4(e0 * inv, e1 * inv, e2 * inv, e3 * inv);
    }
}

// ---------------- MFMA bf16 GEMM: C = act(A@W + bias) [*mul] ---------------
// 512 threads / 8 waves: wave w -> rows [wr*64,+64), cols [wc*32,+32).
// Double-buffered LDS, ONE barrier per K-step:
//   STAGE(next) ; reads+MFMA(cur) ; vmcnt(0) ; barrier
template <int OUTBF>
__global__ __launch_bounds__(512) void gemm_bf16(
    const unsigned short* __restrict__ A, const unsigned short* __restrict__ Wt,
    const float* __restrict__ bias, const float* __restrict__ bias2,
    const unsigned short* __restrict__ mul,
    void* __restrict__ Cv, int N, int K, int lda, int nsplit,
    long sAe, long sWe, long sBe, long sMe, long sCe, int act)
{
    __shared__ unsigned short As[2][128 * 64];
    __shared__ unsigned short Bs[2][128 * 64];
    int e = blockIdx.z;
    A += (long)e * sAe; Wt += (long)e * sWe;
    bias += (long)e * sBe; bias2 += (long)e * sBe;
    if (mul) mul += (long)e * sMe;
    int tid = threadIdx.x;
    int row0 = blockIdx.y * 128, col0 = blockIdx.x * 128;
    int wid = tid >> 6, lane = tid & 63;
    int wr = wid >> 2, wc = wid & 3;
    int l15 = lane & 15, l4 = lane >> 4;
    int r8 = lane >> 3, sg = lane & 7;
    float4v acc[4][2];
    #pragma unroll
    for (int i = 0; i < 4; ++i)
        #pragma unroll
        for (int j = 0; j < 2; ++j) acc[i][j] = (float4v){0.f, 0.f, 0.f, 0.f};

    auto STAGE = [&](int buf, int k0) {
        #pragma unroll
        for (int c = 0; c < 2; ++c) {
            int chunk = wid * 2 + c;                  // 0..15
            int rowA = chunk * 8 + r8;
            int segA = (sg ^ (rowA & 7)) * 8;
            gload_lds16(A + (long)(row0 + rowA) * lda + k0 + segA,
                        (unsigned short*)((char*)As[buf] + chunk * 1024));
            gload_lds16(Wt + (long)(col0 + rowA) * K + k0 + segA,
                        (unsigned short*)((char*)Bs[buf] + chunk * 1024));
        }
    };
    int nt = K >> 6;
    STAGE(0, 0);
    asm volatile("s_waitcnt vmcnt(0)" ::: "memory");
    __builtin_amdgcn_s_barrier();
    for (int t = 0; t < nt; ++t) {
        int cur = t & 1;
        if (t + 1 < nt) STAGE(cur ^ 1, (t + 1) << 6);
        __builtin_amdgcn_sched_barrier(0);
        #pragma unroll
        for (int kk = 0; kk < 2; ++kk) {
            short8v af[4], bq[2];
            int bytec = kk * 64 + l4 * 16;
            #pragma unroll
            for (int m = 0; m < 4; ++m) {
                int r = wr * 64 + m * 16 + l15;
                af[m] = *reinterpret_cast<const short8v*>(
                    (char*)As[cur] + r * 128 + (bytec ^ ((r & 7) << 4)));
            }
            #pragma unroll
            for (int n = 0; n < 2; ++n) {
                int r = wc * 32 + n * 16 + l15;
                bq[n] = *reinterpret_cast<const short8v*>(
                    (char*)Bs[cur] + r * 128 + (bytec ^ ((r & 7) << 4)));
            }
            #pragma unroll
            for (int m = 0; m < 4; ++m)
                #pragma unroll
                for (int n = 0; n < 2; ++n)
                    acc[m][n] = __builtin_amdgcn_mfma_f32_16x16x32_bf16(
                        af[m], bq[n], acc[m][n], 0, 0, 0);
        }
        __builtin_amdgcn_sched_barrier(0);
        if (t + 1 < nt) {
            // all waves' ds_reads of cur are complete (consumed by MFMA);
            // vmcnt(0) certifies next buffer staged; barrier releases it and
            // permits iter t+1's STAGE to overwrite cur.
            asm volatile("s_waitcnt vmcnt(0)" ::: "memory");
            __builtin_amdgcn_s_barrier();
        }
    }
    float* Cf = (float*)Cv + (long)e * sCe;
    unsigned short* Cb = (unsigned short*)Cv + (long)e * sCe;
    #pragma unroll
    for (int n = 0; n < 2; ++n) {
        int col = col0 + wc * 32 + n * 16 + l15;
        float bia = (col < nsplit) ? bias[col] : bias2[col - nsplit];
        #pragma unroll
        for (int m = 0; m < 4; ++m) {
            #pragma unroll
            for (int r = 0; r < 4; ++r) {
                long row = row0 + wr * 64 + m * 16 + l4 * 4 + r;
                float v = acc[m][n][r] + bia;
                if (act == 1) v = fmaxf(v, 0.f);
                else if (act == 2) v = 1.f / (1.f + __expf(-v));
                else if (act == 3) v = ftanh(v);
                if (mul) v *= bf2f(mul[row * N + col]);
                if (OUTBF) Cb[row * N + col] = f2bf(v);
                else       Cf[row * N + col] = v;
            }
        }
    }
}

// ---------------- LayerNorm bf16 in/out (DIM=1024) -------------------------
template <int DIM>
__global__ __launch_bounds__(256) void ln_bf16(
    unsigned short* __restrict__ buf, const float* __restrict__ g,
    const float* __restrict__ beta)
{
    constexpr int PT = DIM / 256;
    __shared__ float sbuf[4];
    int row = blockIdx.x, e = row >> 10;
    unsigned short* p = buf + (long)row * DIM;
    const float* gp = g + (long)e * DIM;
    const float* bp = beta + (long)e * DIM;
    int tid = threadIdx.x;
    float v[PT];
    ushort4 u = *reinterpret_cast<const ushort4*>(p + tid * PT);
    v[0] = bf2f(u.x); v[1] = bf2f(u.y); v[2] = bf2f(u.z); v[3] = bf2f(u.w);
    float s = v[0] + v[1] + v[2] + v[3];
    #pragma unroll
    for (int off = 32; off; off >>= 1) s += __shfl_down(s, off);
    if ((tid & 63) == 0) sbuf[tid >> 6] = s;
    __syncthreads();
    float mean = (sbuf[0] + sbuf[1] + sbuf[2] + sbuf[3]) / (float)DIM;
    __syncthreads();
    float vs = 0.f;
    #pragma unroll
    for (int i = 0; i < PT; ++i) { float d = v[i] - mean; vs += d * d; }
    #pragma unroll
    for (int off = 32; off; off >>= 1) vs += __shfl_down(vs, off);
    if ((tid & 63) == 0) sbuf[tid >> 6] = vs;
    __syncthreads();
    float var = (sbuf[0] + sbuf[1] + sbuf[2] + sbuf[3]) / (float)DIM;
    float rstd = rsqrtf(var + 1e-5f);
    ushort4 o;
    o.x = f2bf((v[0] - mean) * rstd * gp[tid * PT + 0] + bp[tid * PT + 0]);
    o.y = f2bf((v[1] - mean) * rstd * gp[tid * PT + 1] + bp[tid * PT + 1]);
    o.z = f2bf((v[2] - mean) * rstd * gp[tid * PT + 2] + bp[tid * PT + 2]);
    o.w = f2bf((v[3] - mean) * rstd * gp[tid * PT + 3] + bp[tid * PT + 3]);
    *reinterpret_cast<ushort4*>(p + tid * PT) = o;
}

// ---------------- LayerNorm fp32 in-place (DIM=512 final) ------------------
template <int DIM>
__global__ __launch_bounds__(256) void ln_kernel(
    float* __restrict__ buf, const float* __restrict__ g,
    const float* __restrict__ beta)
{
    constexpr int PT = DIM / 256;
    __shared__ float sbuf[4];
    int row = blockIdx.x, e = row >> 10;
    float* p = buf + (long)row * DIM;
    const float* gp = g + (long)e * DIM;
    const float* bp = beta + (long)e * DIM;
    int tid = threadIdx.x;
    float v[PT];
    float s = 0.f;
    #pragma unroll
    for (int i = 0; i < PT; ++i) { v[i] = p[tid + i * 256]; s += v[i]; }
    #pragma unroll
    for (int off = 32; off; off >>= 1) s += __shfl_down(s, off);
    if ((tid & 63) == 0) sbuf[tid >> 6] = s;
    __syncthreads();
    float mean = (sbuf[0] + sbuf[1] + sbuf[2] + sbuf[3]) / (float)DIM;
    __syncthreads();
    float vs = 0.f;
    #pragma unroll
    for (int i = 0; i < PT; ++i) { float d = v[i] - mean; vs += d * d; }
    #pragma unroll
    for (int off = 32; off; off >>= 1) vs += __shfl_down(vs, off);
    if ((tid & 63) == 0) sbuf[tid >> 6] = vs;
    __syncthreads();
    float var = (sbuf[0] + sbuf[1] + sbuf[2] + sbuf[3]) / (float)DIM;
    float rstd = rsqrtf(var + 1e-5f);
    #pragma unroll
    for (int i = 0; i < PT; ++i)
        p[tid + i * 256] = (v[i] - mean) * rstd * gp[tid + i * 256] + bp[tid + i * 256];
}

// ---------------- fused attention, bf16 in/out -----------------------------
__global__ __launch_bounds__(128) void attn_bf16(
    const unsigned short* __restrict__ qkv, unsigned short* __restrict__ o)
{
    __shared__ __align__(16) float Ks[128][64];
    __shared__ __align__(16) float Vs[128][64];
    int id = blockIdx.x;
    int hd = id & 15, b = (id >> 4) & 7, e = id >> 7;
    int tid = threadIdx.x;
    const long base = ((long)e * 1024 + b * 128) * 3072 + hd * 64;
    #pragma unroll
    for (int i = 0; i < 8; ++i) {
        int idx = i * 128 + tid;
        int row = idx >> 3, f8 = (idx & 7) * 8;
        short8v kv = *reinterpret_cast<const short8v*>(&qkv[base + (long)row * 3072 + 1024 + f8]);
        short8v vv = *reinterpret_cast<const short8v*>(&qkv[base + (long)row * 3072 + 2048 + f8]);
        #pragma unroll
        for (int j = 0; j < 8; ++j) {
            Ks[row][f8 + j] = bf2f((unsigned short)kv[j]);
            Vs[row][f8 + j] = bf2f((unsigned short)vv[j]);
        }
    }
    __syncthreads();
    float q[64];
    #pragma unroll
    for (int f = 0; f < 8; ++f) {
        short8v qv = *reinterpret_cast<const short8v*>(&qkv[base + (long)tid * 3072 + f * 8]);
        #pragma unroll
        for (int j = 0; j < 8; ++j) q[f * 8 + j] = bf2f((unsigned short)qv[j]);
    }
    float m = -__builtin_huge_valf(), l = 0.f;
    float oa[64];
    #pragma unroll
    for (int d = 0; d < 64; ++d) oa[d] = 0.f;
    for (int j = 0; j < 128; ++j) {
        float s = 0.f;
        #pragma unroll
        for (int d = 0; d < 64; ++d) s = fmaf(q[d], Ks[j][d], s);
        s *= 0.125f;
        float mn = fmaxf(m, s);
        float corr = __expf(m - mn);
        float pj = __expf(s - mn);
        l = l * corr + pj;
        #pragma unroll
        for (int d = 0; d < 64; ++d) oa[d] = oa[d] * corr + pj * Vs[j][d];
        m = mn;
    }
    float inv = 1.f / l;
    unsigned short* op = o + ((long)e * 1024 + b * 128 + tid) * 1024 + hd * 64;
    #pragma unroll
    for (int f = 0; f < 8; ++f) {
        short8v ov;
        #pragma unroll
        for (int j = 0; j < 8; ++j) ov[j] = (short)f2bf(oa[f * 8 + j] * inv);
        *reinterpret_cast<short8v*>(&op[f * 8]) = ov;
    }
}

// ---------------- persistent LSTM (round-5 exact) ---------------------------
__global__ __launch_bounds__(512, 4) void lstm_persistent(
    const unsigned short* __restrict__ pre, const unsigned short* __restrict__ whtf,
    const unsigned short* __restrict__ whtb, unsigned short* __restrict__ hstate,
    unsigned short* __restrict__ memb, unsigned int* __restrict__ sync)
{
    __shared__ unsigned short hA[16 * 1024];       // 32KB swizzled A-operand
    __shared__ float zred[4][2][8][16];            // gate, khalf, batch, col
    int bid = blockIdx.x;
    int ed = bid & 7, cb = bid >> 3;
    int e = ed >> 1, dir = ed & 1;
    const unsigned short* Wt = (dir ? whtb : whtf) + (long)e * 4096 * 1024;
    unsigned int* arr = sync + ed * 64;            // [8][64] arrival slots
    int tid = threadIdx.x;
    int w = tid >> 6, lane = tid & 63, l15 = lane & 15, l4 = lane >> 4;
    int g = w >> 1, kh = w & 1;
    // one-time: weight fragments into registers
    short8v wf[16];
    const unsigned short* wp =
        Wt + ((long)(g * 1024 + cb * 16 + l15)) * 1024 + kh * 512 + l4 * 8;
    #pragma unroll
    for (int ks = 0; ks < 16; ++ks)
        wf[ks] = *reinterpret_cast<const short8v*>(wp + ks * 32);
    // one-time: zero pad rows 8..15 of hA
    short8v z8 = {0, 0, 0, 0, 0, 0, 0, 0};
    for (int i = tid; i < 8 * 128; i += 512) {
        int r = 8 + (i >> 7), sb = (i & 127) * 16;
        *reinterpret_cast<short8v*>((char*)hA + r * 2048 + (sb ^ ((r & 7) << 4))) = z8;
    }
    float c0 = 0.f, c1 = 0.f;                      // c-state (gate threads)
    int gp = tid & 7, gb = tid >> 3;               // gate mapping (tid<64)
    for (int s = 0; s < 128; ++s) {
        int t = dir ? 127 - s : s;
        const unsigned long long* hin64 = reinterpret_cast<const unsigned long long*>(
            hstate + (long)(s & 1) * 65536 + (long)ed * 8192);
        __syncthreads();
        // stage h(s-1): coherent 8B loads -> swizzled LDS
        #pragma unroll
        for (int i = 0; i < 4; ++i) {
            int idx = tid + 512 * i;               // 0..2047 (8B units)
            unsigned long long v = __hip_atomic_load(
                hin64 + idx, __ATOMIC_RELAXED, __HIP_MEMORY_SCOPE_AGENT);
            int r = idx >> 8, sb = (idx & 255) * 8;
            *reinterpret_cast<unsigned long long*>(
                (char*)hA + r * 2048 + (sb ^ ((r & 7) << 4))) = v;
        }
        // prefetch pre for gate threads
        float pz[8];
        if (tid < 64) {
            const unsigned short* prow =
                pre + (((long)e * 1024) + gb * 128 + t) * 8192 + dir * 4096 + cb * 16 + gp * 2;
            #pragma unroll
            for (int gg = 0; gg < 4; ++gg) {
                unsigned int u = *reinterpret_cast<const unsigned int*>(prow + gg * 1024);
                pz[gg * 2]     = bf2f((unsigned short)(u & 0xffff));
                pz[gg * 2 + 1] = bf2f((unsigned short)(u >> 16));
            }
        }
        __syncthreads();
        // MFMA: acc = h @ Wh[:, mycols]
        float4v acc = (float4v){0.f, 0.f, 0.f, 0.f};
        int abase = l15 * 2048, aswz = (l15 & 7) << 4;
        #pragma unroll
        for (int ks = 0; ks < 16; ++ks) {
            short8v a = *reinterpret_cast<const short8v*>(
                (char*)hA + abase + (((kh * 512 + ks * 32) * 2 + l4 * 16) ^ aswz));
            acc = __builtin_amdgcn_mfma_f32_16x16x32_bf16(a, wf[ks], acc, 0, 0, 0);
        }
        if (l4 < 2) {
            #pragma unroll
            for (int r = 0; r < 4; ++r)
                zred[g][kh][l4 * 4 + r][l15] = acc[r];
        }
        __syncthreads();
        if (tid < 64) {
            int col0 = gp * 2;
            float h2[2];
            #pragma unroll
            for (int cc = 0; cc < 2; ++cc) {
                int col = col0 + cc;
                float zi = zred[0][0][gb][col] + zred[0][1][gb][col] + pz[0 + cc];
                float zf = zred[1][0][gb][col] + zred[1][1][gb][col] + pz[2 + cc];
                float zg = zred[2][0][gb][col] + zred[2][1][gb][col] + pz[4 + cc];
                float zo = zred[3][0][gb][col] + zred[3][1][gb][col] + pz[6 + cc];
                float ig = 1.f / (1.f + __expf(-zi));
                float fg = 1.f / (1.f + __expf(-zf));
                float gv = tanhf(zg);
                float og = 1.f / (1.f + __expf(-zo));
                float cv = cc ? c1 : c0;
                cv = fg * cv + ig * gv;
                if (cc) c1 = cv; else c0 = cv;
                h2[cc] = og * tanhf(cv);
            }
            unsigned int hv = (unsigned int)f2bf(h2[0]) | ((unsigned int)f2bf(h2[1]) << 16);
            int hcol = cb * 16 + col0;
            unsigned int* hout32 = reinterpret_cast<unsigned int*>(
                hstate + (long)((s & 1) ^ 1) * 65536 + (long)ed * 8192);
            __hip_atomic_store(hout32 + (gb * 1024 + hcol) / 2, hv,
                               __ATOMIC_RELAXED, __HIP_MEMORY_SCOPE_AGENT);
            *reinterpret_cast<unsigned int*>(
                memb + (((long)e * 8 + gb) * 128 + t) * 2048 + dir * 1024 + hcol) = hv;
        }
        if (s == 127) break;           // last step: no consumer, skip barrier
        __syncthreads();               // drains vmcnt: h stores at coherence pt
        // single-hop all-to-all: signal own slot, wave0 sweeps all 64
        if (tid == 0)
            __hip_atomic_store(arr + cb, (unsigned)(s + 1), __ATOMIC_RELAXED,
                               __HIP_MEMORY_SCOPE_AGENT);
        if (tid < 64) {
            while (__hip_atomic_load(arr + tid, __ATOMIC_RELAXED,
                                     __HIP_MEMORY_SCOPE_AGENT) < (unsigned)(s + 1))
                __builtin_amdgcn_s_sleep(1);
        }
        // top-of-loop __syncthreads() completes the barrier block-wide
    }
}

// ---------------- routed combine (fp32) ------------------------------------
__global__ __launch_bounds__(256) void combine_kernel(
    const float* __restrict__ outs, const float* __restrict__ router,
    float* __restrict__ out)
{
    int idx = blockIdx.x * 256 + threadIdx.x;
    int token = idx >> 7, q = (idx & 127) * 4;
    float4 r = *reinterpret_cast<const float4*>(&router[token * 4]);
    const float* bp = outs + (long)token * 512 + q;
    float4 v0 = *reinterpret_cast<const float4*>(bp);
    float4 v1 = *reinterpret_cast<const float4*>(bp + 524288);
    float4 v2 = *reinterpret_cast<const float4*>(bp + 1048576);
    float4 v3 = *reinterpret_cast<const float4*>(bp + 1572864);
    float4 a;
    a.x = r.x * v0.x + r.y * v1.x + r.z * v2.x + r.w * v3.x;
    a.y = r.x * v0.y + r.y * v1.y + r.z * v2.y + r.w * v3.y;
    a.z = r.x * v0.z + r.y * v1.z + r.z * v2.z + r.w * v3.z;
    a.w = r.x * v0.w + r.y * v1.w + r.z * v2.w + r.w * v3.w;
    *reinterpret_cast<float4*>(&out[(long)token * 512 + q]) = a;
}

extern "C" void kernel_launch(void* const* d_in, const int* in_sizes, int n_in,
                              void* d_out, int out_size, void* d_ws, size_t ws_size,
                              hipStream_t stream)
{
    (void)in_sizes; (void)n_in; (void)out_size; (void)ws_size;
    const float* x        = (const float*)d_in[0];
    const float* router_w = (const float*)d_in[1];
    const float* router_b = (const float*)d_in[2];
    const float* enc_w1   = (const float*)d_in[3];
    const float* enc_b1   = (const float*)d_in[4];
    const float* enc_w2   = (const float*)d_in[5];
    const float* enc_b2   = (const float*)d_in[6];
    const float* enc_g    = (const float*)d_in[7];
    const float* enc_beta = (const float*)d_in[8];
    const float* aiw      = (const float*)d_in[9];
    const float* aib      = (const float*)d_in[10];
    const float* aow      = (const float*)d_in[11];
    const float* aob      = (const float*)d_in[12];
    const float* wif      = (const float*)d_in[13];
    const float* whf      = (const float*)d_in[14];
    const float* bfv      = (const float*)d_in[15];
    const float* wib      = (const float*)d_in[16];
    const float* whb      = (const float*)d_in[17];
    const float* bbv      = (const float*)d_in[18];
    const float* sw1      = (const float*)d_in[19];
    const float* sb1      = (const float*)d_in[20];
    const float* sw2      = (const float*)d_in[21];
    const float* sb2      = (const float*)d_in[22];
    const float* tw1      = (const float*)d_in[23];
    const float* tb1      = (const float*)d_in[24];
    const float* tw2      = (const float*)d_in[25];
    const float* tb2      = (const float*)d_in[26];
    const float* dw1      = (const float*)d_in[27];
    const float* db1      = (const float*)d_in[28];
    const float* dw2      = (const float*)d_in[29];
    const float* db2      = (const float*)d_in[30];
    const float* dg       = (const float*)d_in[31];
    const float* dbeta    = (const float*)d_in[32];
    float* out = (float*)d_out;

    const long m = 1024L * 1024L;
    unsigned short* U = (unsigned short*)d_ws;
    unsigned short* ew1T = U;               // 2m
    unsigned short* ew2T = U + 2 * m;       // 4m
    unsigned short* aiwT = U + 6 * m;       // 12m
    unsigned short* aowT = U + 18 * m;      // 4m
    unsigned short* wiT  = U + 22 * m;      // 32m: [e][fwd4096|bwd4096][1024]
    unsigned short* whtf = U + 54 * m;      // 16m
    unsigned short* whtb = U + 70 * m;      // 16m
    unsigned short* gw1T = U + 86 * m;      // 16m: per-e 4m slab (sw1|tw1 cols)
    unsigned short* sw2T = U + 102 * m;     // 4m
    unsigned short* tw2T = U + 106 * m;     // 4m
    unsigned short* dw1T = U + 110 * m;     // 4m
    unsigned short* dw2T = U + 114 * m;     // 2m
    unsigned short* xb   = U + 116 * m;     // 0.5m
    unsigned short* hbuf = xb + 524288;     // 4m
    unsigned short* t1   = hbuf + 4 * m;    // 4m
    unsigned short* t2   = t1 + 4 * m;      // 4m
    unsigned short* pre  = t2 + 4 * m;      // 32m (early: qkv; late: gate1 out)
    unsigned short* memb = pre + 32 * m;    // 8m
    unsigned short* hstate = memb + 8 * m;  // 262144 ushorts (2 buffers)
    float* F      = (float*)(U + 170 * m);
    float* outs   = F;                      // 2m floats
    float* router = outs + 2 * m;           // 4096
    unsigned int* syncv = (unsigned int*)(router + 4096);  // 1024 uints

    hipMemsetAsync(hstate, 0, 65536 * sizeof(unsigned short), stream);
    hipMemsetAsync(syncv, 0, 1024 * sizeof(unsigned int), stream);

    // one-time conversions: x + all weights (one batched dispatch)
    cvt_bf16_kernel<<<512, 256, 0, stream>>>(x, xb, 131072);
    {
        TransJobs J;
        const float* srcs[14] = {enc_w1, enc_w2, aiw, aow, wif, wib, whf, whb,
                                 sw1, tw1, sw2, tw2, dw1, dw2};
        unsigned short* dsts[14] = {ew1T, ew2T, aiwT, aowT, wiT, wiT + 4096 * 1024L,
                                    whtf, whtb, gw1T, gw1T + 2 * m, sw2T, tw2T, dw1T, dw2T};
        int Ks[14] = {512, 1024, 1024, 1024, 1024, 1024, 1024, 1024,
                      2048, 2048, 1024, 1024, 1024, 1024};
        int Ns[14] = {1024, 1024, 3072, 1024, 4096, 4096, 4096, 4096,
                      1024, 1024, 1024, 1024, 1024, 512};
        long sWes[14] = {512 * 1024L, m, 3 * m, m, 4 * m, 4 * m, 4 * m, 4 * m,
                         2 * m, 2 * m, m, m, m, 512 * 1024L};
        long sTes[14] = {512 * 1024L, m, 3 * m, m, 8 * m, 8 * m, 4 * m, 4 * m,
                         4 * m, 4 * m, m, m, m, 512 * 1024L};
        int pfx = 0;
        J.prefix[0] = 0;
        for (int i = 0; i < 14; ++i) {
            J.src[i] = srcs[i]; J.dst[i] = dsts[i];
            J.K[i] = Ks[i]; J.N[i] = Ns[i];
            J.sWe[i] = sWes[i]; J.sTe[i] = sTes[i];
            pfx += (Ns[i] >> 5) * (Ks[i] >> 6) * 4;
            J.prefix[i + 1] = pfx;
        }
        transpose_all<<<pfx, 256, 0, stream>>>(J);
    }

    router_kernel<<<1024, 64, 0, stream>>>(x, router_w, router_b, router);

    // encoder
    gemm_bf16<1><<<dim3(8, 8, 4), 512, 0, stream>>>(xb, ew1T, enc_b1, enc_b1, nullptr, t1,
        1024, 512, 512, 1024, 0L, 512 * 1024L, 1024L, 0L, m, 1);
    gemm_bf16<1><<<dim3(8, 8, 4), 512, 0, stream>>>(t1, ew2T, enc_b2, enc_b2, nullptr, hbuf,
        1024, 1024, 1024, 1024, m, m, 1024L, 0L, m, 0);
    ln_bf16<1024><<<4096, 256, 0, stream>>>(hbuf, enc_g, enc_beta);
    // attention (qkv in pre region)
    gemm_bf16<1><<<dim3(24, 8, 4), 512, 0, stream>>>(hbuf, aiwT, aib, aib, nullptr, pre,
        3072, 1024, 1024, 3072, m, 3 * m, 3072L, 0L, 3 * m, 0);
    attn_bf16<<<512, 128, 0, stream>>>(pre, t1);
    gemm_bf16<1><<<dim3(8, 8, 4), 512, 0, stream>>>(t1, aowT, aob, aob, nullptr, hbuf,
        1024, 1024, 1024, 1024, m, m, 1024L, 0L, m, 0);
    // LSTM input projections, merged fwd|bwd: pre[e][tok][8192]
    gemm_bf16<1><<<dim3(64, 8, 4), 512, 0, stream>>>(hbuf, wiT, bfv, bbv, nullptr, pre,
        8192, 1024, 1024, 4096, m, 8 * m, 4096L, 0L, 8 * m, 0);
    // recurrence: one persistent kernel
    lstm_persistent<<<512, 512, 0, stream>>>(pre, whtf, whtb, hstate, memb, syncv);
    // gate branches: merged first layer (N=2048: sig|tan), out -> pre region
    unsigned short* g1o = pre;               // [E][1024][2048] bf16
    gemm_bf16<1><<<dim3(16, 8, 4), 512, 0, stream>>>(memb, gw1T, sb1, tb1, nullptr, g1o,
        2048, 2048, 2048, 1024, 2 * m, 4 * m, 1024L, 0L, 2 * m, 1);
    gemm_bf16<1><<<dim3(8, 8, 4), 512, 0, stream>>>(g1o, sw2T, sb2, sb2, nullptr, t2,
        1024, 1024, 2048, 1024, 2 * m, m, 1024L, 0L, m, 2);
    gemm_bf16<1><<<dim3(8, 8, 4), 512, 0, stream>>>(g1o + 1024, tw2T, tb2, tb2, t2, hbuf,
        1024, 1024, 2048, 1024, 2 * m, m, 1024L, m, m, 3);
    // decoder
    gemm_bf16<1><<<dim3(8, 8, 4), 512, 0, stream>>>(hbuf, dw1T, db1, db1, nullptr, t1,
        1024, 1024, 1024, 1024, m, m, 1024L, 0L, m, 1);
    gemm_bf16<0><<<dim3(4, 8, 4), 512, 0, stream>>>(t1, dw2T, db2, db2, nullptr, outs,
        512, 1024, 1024, 512, m, 512 * 1024L, 512L, 0L, 512 * 1024L, 0);
    ln_kernel<512><<<4096, 256, 0, stream>>>(outs, dg, dbeta);
    combine_kernel<<<512, 256, 0, stream>>>(outs, router, out);
}